// Round 2
// baseline (4760.896 us; speedup 1.0000x reference)
//
#include <hip/hip_runtime.h>
#include <hip/hip_bf16.h>
#include <math.h>

#define B_   8
#define L_   1024
#define DM_  256
#define NL_  4
#define ED_  512
#define NS_  16
#define DC_  4
#define RK_  16
#define CD_  64
#define Q_   2

__device__ __forceinline__ float geluf(float x) {
    return 0.5f * x * (1.0f + erff(x * 0.70710678118654752f));
}
__device__ __forceinline__ float siluf(float x) {
    return x / (1.0f + expf(-x));
}
__device__ __forceinline__ float softplusf(float x) {
    return (x > 20.0f) ? x : log1pf(expf(x));
}

// 256-thread block sum; sm must have >= 4 floats
__device__ __forceinline__ float block_sum256(float v, float* sm) {
    int tid = threadIdx.x;
    #pragma unroll
    for (int off = 32; off > 0; off >>= 1) v += __shfl_down(v, off, 64);
    __syncthreads();
    if ((tid & 63) == 0) sm[tid >> 6] = v;
    __syncthreads();
    return sm[0] + sm[1] + sm[2] + sm[3];
}

// ---------------- embed: x[b,l,:] = (l>0 ? tok_embed[tokens[b,l-1]] : 0) + pos_embed[l]
__global__ void k_embed(const int* __restrict__ tokens,
                        const float* __restrict__ tok_embed,
                        const float* __restrict__ pos_embed,
                        float* __restrict__ x) {
    int row = blockIdx.x;           // b*L + l
    int d = threadIdx.x;            // 0..255
    int b = row / L_, l = row % L_;
    float v = pos_embed[l * DM_ + d];
    if (l > 0) {
        int tok = tokens[b * L_ + l - 1];
        v += tok_embed[tok * DM_ + d];
    }
    x[row * DM_ + d] = v;
}

// ---------------- conditioning: cond[b,:] = gelu(T[b]*tw1+tb1) @ tw2 + tb2
__global__ void k_cond(const float* __restrict__ T,
                       const float* __restrict__ tw1, const float* __restrict__ tb1,
                       const float* __restrict__ tw2, const float* __restrict__ tb2,
                       float* __restrict__ cond) {
    __shared__ float hbuf[B_ * CD_];
    int c = threadIdx.x;            // 0..63
    for (int b = 0; b < B_; b++) {
        float t = T[b];
        hbuf[b * CD_ + c] = geluf(t * tw1[c] + tb1[c]);
    }
    __syncthreads();
    for (int b = 0; b < B_; b++) {
        float acc = tb2[c];
        for (int cc = 0; cc < CD_; cc++)
            acc += hbuf[b * CD_ + cc] * tw2[cc * CD_ + c];
        cond[b * CD_ + c] = acc;
    }
}

// ---------------- per-layer adaLN params: ss[b,j] = cond[b] @ apw[i] + apb[i]
__global__ void k_ss(const float* __restrict__ cond,
                     const float* __restrict__ apw, const float* __restrict__ apb,
                     float* __restrict__ ss, int layer) {
    int b = blockIdx.x;             // 0..7
    int j = threadIdx.x;            // 0..511
    const float* w = apw + (size_t)layer * CD_ * 2 * DM_;
    float acc = apb[layer * 2 * DM_ + j];
    for (int c = 0; c < CD_; c++)
        acc += cond[b * CD_ + c] * w[c * 2 * DM_ + j];
    ss[b * 2 * DM_ + j] = acc;
}

// ---------------- LN + adaLN modulation: xn = (1+sc)*LN(x)*g+b + sh
__global__ void k_lnmod(const float* __restrict__ x,
                        const float* __restrict__ ag, const float* __restrict__ ab,
                        const float* __restrict__ ss,
                        float* __restrict__ xn, int layer) {
    __shared__ float sm[4];
    int row = blockIdx.x;           // b*L+l
    int d = threadIdx.x;            // 0..255
    int b = row / L_;
    float v = x[row * DM_ + d];
    float mean = block_sum256(v, sm) * (1.0f / DM_);
    float dv = v - mean;
    float var = block_sum256(dv * dv, sm) * (1.0f / DM_);
    float rstd = rsqrtf(var + 1e-5f);
    float ln = dv * rstd * ag[layer * DM_ + d] + ab[layer * DM_ + d];
    float sc = ss[b * 2 * DM_ + d];
    float sh = ss[b * 2 * DM_ + DM_ + d];
    xn[row * DM_ + d] = (1.0f + sc) * ln + sh;
}

// ---------------- generic tiled fp32 GEMM: C[M,N] (+)= A[M,K] @ Bw[K,N]
__global__ void k_gemm(const float* __restrict__ A, int lda,
                       const float* __restrict__ Bw, int ldb,
                       float* __restrict__ C, int ldc,
                       int M, int N, int K, int accum) {
    __shared__ float As[64][17];
    __shared__ float Bs[16][65];
    int tid = threadIdx.x;
    int tx = tid & 15, ty = tid >> 4;
    int row0 = blockIdx.y * 64, col0 = blockIdx.x * 64;
    float acc[4][4] = {};
    for (int k0 = 0; k0 < K; k0 += 16) {
        {
            int c = tid & 15, r = tid >> 4;
            #pragma unroll
            for (int rr = r; rr < 64; rr += 16) {
                int gr = row0 + rr, gc = k0 + c;
                As[rr][c] = (gr < M && gc < K) ? A[(size_t)gr * lda + gc] : 0.f;
            }
        }
        {
            int c = tid & 63, r = tid >> 6;
            #pragma unroll
            for (int rr = r; rr < 16; rr += 4) {
                int gr = k0 + rr, gc = col0 + c;
                Bs[rr][c] = (gr < K && gc < N) ? Bw[(size_t)gr * ldb + gc] : 0.f;
            }
        }
        __syncthreads();
        #pragma unroll
        for (int kk = 0; kk < 16; kk++) {
            float a[4], b[4];
            #pragma unroll
            for (int i = 0; i < 4; i++) a[i] = As[ty * 4 + i][kk];
            #pragma unroll
            for (int j = 0; j < 4; j++) b[j] = Bs[kk][tx * 4 + j];
            #pragma unroll
            for (int i = 0; i < 4; i++)
                #pragma unroll
                for (int j = 0; j < 4; j++)
                    acc[i][j] += a[i] * b[j];
        }
        __syncthreads();
    }
    #pragma unroll
    for (int i = 0; i < 4; i++) {
        int gr = row0 + ty * 4 + i;
        if (gr >= M) continue;
        #pragma unroll
        for (int j = 0; j < 4; j++) {
            int gc = col0 + tx * 4 + j;
            if (gc >= N) continue;
            if (accum) C[(size_t)gr * ldc + gc] += acc[i][j];
            else       C[(size_t)gr * ldc + gc] = acc[i][j];
        }
    }
}

// ---------------- causal depthwise conv (DC=4) + SiLU: xz[:,:, :ED] -> xs
__global__ void k_conv(const float* __restrict__ xz,
                       const float* __restrict__ conv_w, const float* __restrict__ conv_b,
                       float* __restrict__ xs, int layer) {
    int t = blockIdx.x * blockDim.x + threadIdx.x;   // b*L*ED
    int e = t % ED_;
    int row = t / ED_;
    int b = row / L_, l = row % L_;
    float acc = conv_b[layer * ED_ + e];
    const float* w = conv_w + ((size_t)layer * ED_ + e) * DC_;
    #pragma unroll
    for (int k = 0; k < DC_; k++) {
        int ll = l - (DC_ - 1) + k;
        if (ll >= 0)
            acc += xz[((size_t)(b * L_ + ll)) * (2 * ED_) + e] * w[k];
    }
    xs[(size_t)row * ED_ + e] = siluf(acc);
}

// ---------------- dlt = softplus(xd[:,:16] @ dt_w + dt_b)
__global__ void k_dlt(const float* __restrict__ xd,
                      const float* __restrict__ dt_w, const float* __restrict__ dt_b,
                      float* __restrict__ dlt, int layer) {
    int t = blockIdx.x * blockDim.x + threadIdx.x;   // b*L*ED
    int e = t % ED_;
    int row = t / ED_;
    float acc = dt_b[layer * ED_ + e];
    const float* w = dt_w + (size_t)layer * RK_ * ED_;
    #pragma unroll
    for (int r = 0; r < RK_; r++)
        acc += xd[(size_t)row * (RK_ + 2 * NS_) + r] * w[r * ED_ + e];
    dlt[(size_t)row * ED_ + e] = softplusf(acc);
}

// ---------------- selective scan + gate; y aliases dlt (safe: each address is
// read by, and later written by, only its own 16-lane cohort in the same wave;
// NOT marked __restrict__ for that reason)
__global__ void k_scan(const float* dlt,
                       const float* __restrict__ xs,
                       const float* __restrict__ xd,    // Bm at +16, Cm at +32
                       const float* __restrict__ xz,    // z at +ED
                       const float* __restrict__ A_log,
                       const float* __restrict__ Dp,
                       float* y, int layer) {
    int t = blockIdx.x * blockDim.x + threadIdx.x;  // B*ED*NS
    int n = t & (NS_ - 1);
    int g = t >> 4;                                  // b*ED + e
    int e = g % ED_;
    int b = g / ED_;
    float A = -expf(A_log[((size_t)layer * ED_ + e) * NS_ + n]);
    float D = Dp[layer * ED_ + e];
    float h = 0.0f;
    for (int l = 0; l < L_; l++) {
        int row = b * L_ + l;
        float dv = dlt[(size_t)row * ED_ + e];
        float xv = xs[(size_t)row * ED_ + e];
        float Bv = xd[(size_t)row * 48 + 16 + n];
        float Cv = xd[(size_t)row * 48 + 32 + n];
        h = expf(dv * A) * h + (dv * xv) * Bv;
        float p = h * Cv;
        p += __shfl_xor(p, 1, 16);
        p += __shfl_xor(p, 2, 16);
        p += __shfl_xor(p, 4, 16);
        p += __shfl_xor(p, 8, 16);
        if (n == 0) {
            float zv = xz[(size_t)row * (2 * ED_) + ED_ + e];
            y[(size_t)row * ED_ + e] = (p + D * xv) * siluf(zv);
        }
    }
}

// ---------------- final LN + head (DM -> Q=2), fp32 out
__global__ void k_final(const float* __restrict__ x,
                        const float* __restrict__ fg, const float* __restrict__ fb,
                        const float* __restrict__ hw, const float* __restrict__ hb,
                        float* __restrict__ out) {
    __shared__ float sm[4];
    int row = blockIdx.x;
    int d = threadIdx.x;
    float v = x[row * DM_ + d];
    float mean = block_sum256(v, sm) * (1.0f / DM_);
    float dv = v - mean;
    float var = block_sum256(dv * dv, sm) * (1.0f / DM_);
    float rstd = rsqrtf(var + 1e-5f);
    float xf = dv * rstd * fg[d] + fb[d];
    float s0 = block_sum256(xf * hw[d * Q_ + 0], sm);
    float s1 = block_sum256(xf * hw[d * Q_ + 1], sm);
    if (d < Q_) {
        float s = (d == 0) ? s0 : s1;
        out[row * Q_ + d] = s + hb[d];
    }
}

extern "C" void kernel_launch(void* const* d_in, const int* in_sizes, int n_in,
                              void* d_out, int out_size, void* d_ws, size_t ws_size,
                              hipStream_t stream) {
    const int*   tokens    = (const int*)d_in[0];
    const float* T         = (const float*)d_in[1];
    const float* tok_embed = (const float*)d_in[2];
    const float* pos_embed = (const float*)d_in[3];
    const float* tw1       = (const float*)d_in[4];
    const float* tb1       = (const float*)d_in[5];
    const float* tw2       = (const float*)d_in[6];
    const float* tb2       = (const float*)d_in[7];
    const float* ag        = (const float*)d_in[8];
    const float* ab        = (const float*)d_in[9];
    const float* apw       = (const float*)d_in[10];
    const float* apb       = (const float*)d_in[11];
    const float* in_w      = (const float*)d_in[12];
    const float* conv_w    = (const float*)d_in[13];
    const float* conv_b    = (const float*)d_in[14];
    const float* xp_w      = (const float*)d_in[15];
    const float* dt_w      = (const float*)d_in[16];
    const float* dt_b      = (const float*)d_in[17];
    const float* A_log     = (const float*)d_in[18];
    const float* Dp        = (const float*)d_in[19];
    const float* out_w     = (const float*)d_in[20];
    const float* fg        = (const float*)d_in[21];
    const float* fb        = (const float*)d_in[22];
    const float* hw        = (const float*)d_in[23];
    const float* hb        = (const float*)d_in[24];
    float* out = (float*)d_out;

    float* ws = (float*)d_ws;
    const size_t N_X  = (size_t)B_ * L_ * DM_;        // 2,097,152
    const size_t N_XZ = (size_t)B_ * L_ * 2 * ED_;    // 8,388,608
    const size_t N_XS = (size_t)B_ * L_ * ED_;        // 4,194,304
    const size_t N_XD = (size_t)B_ * L_ * 48;         //   393,216
    float* x    = ws;                 size_t off = N_X;
    float* xn   = ws + off;           off += N_X;
    float* xz   = ws + off;           off += N_XZ;
    float* xs   = ws + off;           off += N_XS;
    float* xd   = ws + off;           off += N_XD;
    float* dlt  = ws + off;           off += N_XS;
    float* y    = dlt;                // alias: scan reads dlt[row,e] then writes y[row,e] in-wave
    float* cond = ws + off;           off += B_ * CD_;
    float* ss   = ws + off;           off += B_ * 2 * DM_;

    const int ROWS = B_ * L_;   // 8192

    k_embed<<<ROWS, DM_, 0, stream>>>(tokens, tok_embed, pos_embed, x);
    k_cond<<<1, CD_, 0, stream>>>(T, tw1, tb1, tw2, tb2, cond);

    for (int i = 0; i < NL_; i++) {
        k_ss<<<B_, 2 * DM_, 0, stream>>>(cond, apw, apb, ss, i);
        k_lnmod<<<ROWS, DM_, 0, stream>>>(x, ag, ab, ss, xn, i);
        // xz = xn @ in_w[i]   (8192 x 256 x 1024)
        k_gemm<<<dim3(1024 / 64, ROWS / 64), 256, 0, stream>>>(
            xn, DM_, in_w + (size_t)i * DM_ * 2 * ED_, 2 * ED_,
            xz, 2 * ED_, ROWS, 2 * ED_, DM_, 0);
        k_conv<<<ROWS * ED_ / 256, 256, 0, stream>>>(xz, conv_w, conv_b, xs, i);
        // xd = xs @ xp_w[i]   (8192 x 512 x 48)
        k_gemm<<<dim3(1, ROWS / 64), 256, 0, stream>>>(
            xs, ED_, xp_w + (size_t)i * ED_ * (RK_ + 2 * NS_), RK_ + 2 * NS_,
            xd, RK_ + 2 * NS_, ROWS, RK_ + 2 * NS_, ED_, 0);
        k_dlt<<<ROWS * ED_ / 256, 256, 0, stream>>>(xd, dt_w, dt_b, dlt, i);
        k_scan<<<B_ * ED_ * NS_ / 256, 256, 0, stream>>>(
            dlt, xs, xd, xz, A_log, Dp, y, i);
        // x += y @ out_w[i]   (8192 x 512 x 256)
        k_gemm<<<dim3(DM_ / 64, ROWS / 64), 256, 0, stream>>>(
            y, ED_, out_w + (size_t)i * ED_ * DM_, DM_,
            x, DM_, ROWS, DM_, ED_, 1);
    }

    k_final<<<ROWS, DM_, 0, stream>>>(x, fg, fb, hw, hb, out);
}

// Round 3
// 1867.184 us; speedup vs baseline: 2.5498x; 2.5498x over previous
//
#include <hip/hip_runtime.h>
#include <hip/hip_bf16.h>
#include <math.h>

#define B_   8
#define L_   1024
#define DM_  256
#define NL_  4
#define ED_  512
#define NS_  16
#define DC_  4
#define RK_  16
#define CD_  64
#define Q_   2

#define LC_  64     // scan chunk length
#define PAD_ 68     // padded LDS row stride (floats): 272B = 17*16B -> aligned, conflict-free

__device__ __forceinline__ float geluf(float x) {
    return 0.5f * x * (1.0f + erff(x * 0.70710678118654752f));
}
__device__ __forceinline__ float siluf(float x) {
    return x / (1.0f + __expf(-x));
}
__device__ __forceinline__ float softplusf(float x) {
    return (x > 20.0f) ? x : log1pf(expf(x));
}

// butterfly sum over 16-lane groups: xor1,xor2 via quad_perm DPP; xor4 via ds_swizzle; xor8 via row_ror:8
__device__ __forceinline__ float red16(float p) {
    p += __int_as_float(__builtin_amdgcn_mov_dpp(__float_as_int(p), 0xB1, 0xF, 0xF, true));   // xor1
    p += __int_as_float(__builtin_amdgcn_mov_dpp(__float_as_int(p), 0x4E, 0xF, 0xF, true));   // xor2
    p += __int_as_float(__builtin_amdgcn_ds_swizzle(__float_as_int(p), 0x101F));              // xor4
    p += __int_as_float(__builtin_amdgcn_mov_dpp(__float_as_int(p), 0x128, 0xF, 0xF, true));  // ror8 == xor8 in 16-row
    return p;
}

// 256-thread block sum; sm must have >= 4 floats
__device__ __forceinline__ float block_sum256(float v, float* sm) {
    int tid = threadIdx.x;
    #pragma unroll
    for (int off = 32; off > 0; off >>= 1) v += __shfl_down(v, off, 64);
    __syncthreads();
    if ((tid & 63) == 0) sm[tid >> 6] = v;
    __syncthreads();
    return sm[0] + sm[1] + sm[2] + sm[3];
}

// ---------------- embed
__global__ void k_embed(const int* __restrict__ tokens,
                        const float* __restrict__ tok_embed,
                        const float* __restrict__ pos_embed,
                        float* __restrict__ x) {
    int row = blockIdx.x;
    int d = threadIdx.x;
    int b = row / L_, l = row % L_;
    float v = pos_embed[l * DM_ + d];
    if (l > 0) {
        int tok = tokens[b * L_ + l - 1];
        v += tok_embed[tok * DM_ + d];
    }
    x[row * DM_ + d] = v;
}

// ---------------- conditioning
__global__ void k_cond(const float* __restrict__ T,
                       const float* __restrict__ tw1, const float* __restrict__ tb1,
                       const float* __restrict__ tw2, const float* __restrict__ tb2,
                       float* __restrict__ cond) {
    __shared__ float hbuf[B_ * CD_];
    int c = threadIdx.x;
    for (int b = 0; b < B_; b++) {
        float t = T[b];
        hbuf[b * CD_ + c] = geluf(t * tw1[c] + tb1[c]);
    }
    __syncthreads();
    for (int b = 0; b < B_; b++) {
        float acc = tb2[c];
        for (int cc = 0; cc < CD_; cc++)
            acc += hbuf[b * CD_ + cc] * tw2[cc * CD_ + c];
        cond[b * CD_ + c] = acc;
    }
}

// ---------------- per-layer adaLN params
__global__ void k_ss(const float* __restrict__ cond,
                     const float* __restrict__ apw, const float* __restrict__ apb,
                     float* __restrict__ ss, int layer) {
    int b = blockIdx.x;
    int j = threadIdx.x;
    const float* w = apw + (size_t)layer * CD_ * 2 * DM_;
    float acc = apb[layer * 2 * DM_ + j];
    for (int c = 0; c < CD_; c++)
        acc += cond[b * CD_ + c] * w[c * 2 * DM_ + j];
    ss[b * 2 * DM_ + j] = acc;
}

// ---------------- LN + adaLN modulation
__global__ void k_lnmod(const float* __restrict__ x,
                        const float* __restrict__ ag, const float* __restrict__ ab,
                        const float* __restrict__ ss,
                        float* __restrict__ xn, int layer) {
    __shared__ float sm[4];
    int row = blockIdx.x;
    int d = threadIdx.x;
    int b = row / L_;
    float v = x[row * DM_ + d];
    float mean = block_sum256(v, sm) * (1.0f / DM_);
    float dv = v - mean;
    float var = block_sum256(dv * dv, sm) * (1.0f / DM_);
    float rstd = rsqrtf(var + 1e-5f);
    float ln = dv * rstd * ag[layer * DM_ + d] + ab[layer * DM_ + d];
    float sc = ss[b * 2 * DM_ + d];
    float sh = ss[b * 2 * DM_ + DM_ + d];
    xn[row * DM_ + d] = (1.0f + sc) * ln + sh;
}

// ---------------- generic tiled fp32 GEMM: C[M,N] (+)= A[M,K] @ Bw[K,N]
__global__ void k_gemm(const float* __restrict__ A, int lda,
                       const float* __restrict__ Bw, int ldb,
                       float* __restrict__ C, int ldc,
                       int M, int N, int K, int accum) {
    __shared__ float As[64][17];
    __shared__ float Bs[16][65];
    int tid = threadIdx.x;
    int tx = tid & 15, ty = tid >> 4;
    int row0 = blockIdx.y * 64, col0 = blockIdx.x * 64;
    float acc[4][4] = {};
    for (int k0 = 0; k0 < K; k0 += 16) {
        {
            int c = tid & 15, r = tid >> 4;
            #pragma unroll
            for (int rr = r; rr < 64; rr += 16) {
                int gr = row0 + rr, gc = k0 + c;
                As[rr][c] = (gr < M && gc < K) ? A[(size_t)gr * lda + gc] : 0.f;
            }
        }
        {
            int c = tid & 63, r = tid >> 6;
            #pragma unroll
            for (int rr = r; rr < 16; rr += 4) {
                int gr = k0 + rr, gc = col0 + c;
                Bs[rr][c] = (gr < K && gc < N) ? Bw[(size_t)gr * ldb + gc] : 0.f;
            }
        }
        __syncthreads();
        #pragma unroll
        for (int kk = 0; kk < 16; kk++) {
            float a[4], b[4];
            #pragma unroll
            for (int i = 0; i < 4; i++) a[i] = As[ty * 4 + i][kk];
            #pragma unroll
            for (int j = 0; j < 4; j++) b[j] = Bs[kk][tx * 4 + j];
            #pragma unroll
            for (int i = 0; i < 4; i++)
                #pragma unroll
                for (int j = 0; j < 4; j++)
                    acc[i][j] += a[i] * b[j];
        }
        __syncthreads();
    }
    #pragma unroll
    for (int i = 0; i < 4; i++) {
        int gr = row0 + ty * 4 + i;
        if (gr >= M) continue;
        #pragma unroll
        for (int j = 0; j < 4; j++) {
            int gc = col0 + tx * 4 + j;
            if (gc >= N) continue;
            if (accum) C[(size_t)gr * ldc + gc] += acc[i][j];
            else       C[(size_t)gr * ldc + gc] = acc[i][j];
        }
    }
}

// ---------------- causal depthwise conv (DC=4) + SiLU
__global__ void k_conv(const float* __restrict__ xz,
                       const float* __restrict__ conv_w, const float* __restrict__ conv_b,
                       float* __restrict__ xs, int layer) {
    int t = blockIdx.x * blockDim.x + threadIdx.x;
    int e = t % ED_;
    int row = t / ED_;
    int b = row / L_, l = row % L_;
    float acc = conv_b[layer * ED_ + e];
    const float* w = conv_w + ((size_t)layer * ED_ + e) * DC_;
    #pragma unroll
    for (int k = 0; k < DC_; k++) {
        int ll = l - (DC_ - 1) + k;
        if (ll >= 0)
            acc += xz[((size_t)(b * L_ + ll)) * (2 * ED_) + e] * w[k];
    }
    xs[(size_t)row * ED_ + e] = siluf(acc);
}

// ---------------- dlt = softplus(xd[:,:16] @ dt_w + dt_b)
__global__ void k_dlt(const float* __restrict__ xd,
                      const float* __restrict__ dt_w, const float* __restrict__ dt_b,
                      float* __restrict__ dlt, int layer) {
    int t = blockIdx.x * blockDim.x + threadIdx.x;
    int e = t % ED_;
    int row = t / ED_;
    float acc = dt_b[layer * ED_ + e];
    const float* w = dt_w + (size_t)layer * RK_ * ED_;
    #pragma unroll
    for (int r = 0; r < RK_; r++)
        acc += xd[(size_t)row * (RK_ + 2 * NS_) + r] * w[r * ED_ + e];
    dlt[(size_t)row * ED_ + e] = softplusf(acc);
}

// ---------------- selective scan, LDS-chunked, register-prefetched.
// block: 256 threads = 16 e-lanes x 16 n-lanes; grid: B * ED/16 = 256.
// y aliases dlt: chunk-c y-stores touch rows [c*LC, (c+1)*LC); chunk-(c+1)
// prefetch reads rows [(c+1)*LC, ...) of the same e-columns -> disjoint.
__global__ __launch_bounds__(256) void k_scan(
        const float* dlt, const float* __restrict__ xs,
        const float* __restrict__ xd,    // Bm at +16, Cm at +32 (row stride 48)
        const float* __restrict__ xz,    // z at +ED
        const float* __restrict__ A_log, const float* __restrict__ Dp,
        float* y, int layer) {
    __shared__ float s_dlt[16 * PAD_];
    __shared__ float s_xs [16 * PAD_];
    __shared__ float s_B  [16 * PAD_];
    __shared__ float s_C  [16 * PAD_];
    __shared__ float s_z  [16 * PAD_];
    __shared__ float s_y  [16 * PAD_];

    const int tid = threadIdx.x;
    const int n  = tid & 15;          // state index within group (serial phase)
    const int et = tid >> 4;          // e index within tile (serial phase)
    const int b  = blockIdx.x >> 5;
    const int e0 = (blockIdx.x & 31) << 4;
    const int e  = e0 + et;

    const float A = -__expf(A_log[((size_t)layer * ED_ + e) * NS_ + n]);
    const float D = Dp[layer * ED_ + e];

    // cooperative-load mapping: le = fast index (e-offset or n), lj+16j = l-offset
    const int le = tid & 15;
    const int lj = tid >> 4;
    const int rowbase = b * L_;

    float r_d[4], r_x[4], r_B[4], r_C[4], r_z[4];
    #pragma unroll
    for (int j = 0; j < 4; j++) {
        size_t row = rowbase + lj + 16 * j;
        r_d[j] = dlt[row * ED_ + e0 + le];
        r_x[j] = xs [row * ED_ + e0 + le];
        r_B[j] = xd [row * 48 + 16 + le];
        r_C[j] = xd [row * 48 + 32 + le];
        r_z[j] = xz [row * (2 * ED_) + ED_ + e0 + le];
    }

    float h = 0.0f;
    for (int c = 0; c < L_ / LC_; c++) {
        __syncthreads();   // previous chunk's LDS reads + y stores complete
        #pragma unroll
        for (int j = 0; j < 4; j++) {
            int ll = lj + 16 * j;
            s_dlt[le * PAD_ + ll] = r_d[j];
            s_xs [le * PAD_ + ll] = r_x[j];
            s_B  [le * PAD_ + ll] = r_B[j];
            s_C  [le * PAD_ + ll] = r_C[j];
            s_z  [le * PAD_ + ll] = r_z[j];
        }
        __syncthreads();
        if (c + 1 < L_ / LC_) {       // prefetch next chunk; latency hidden by serial phase
            #pragma unroll
            for (int j = 0; j < 4; j++) {
                size_t row = rowbase + (c + 1) * LC_ + lj + 16 * j;
                r_d[j] = dlt[row * ED_ + e0 + le];
                r_x[j] = xs [row * ED_ + e0 + le];
                r_B[j] = xd [row * 48 + 16 + le];
                r_C[j] = xd [row * 48 + 32 + le];
                r_z[j] = xz [row * (2 * ED_) + ED_ + e0 + le];
            }
        }
        // serial phase: 8 sub-chunks of 8 timesteps, b128 LDS reads
        #pragma unroll
        for (int s = 0; s < LC_ / 8; s++) {
            float4 d0 = *(const float4*)&s_dlt[et * PAD_ + s * 8];
            float4 d1 = *(const float4*)&s_dlt[et * PAD_ + s * 8 + 4];
            float4 x0 = *(const float4*)&s_xs [et * PAD_ + s * 8];
            float4 x1 = *(const float4*)&s_xs [et * PAD_ + s * 8 + 4];
            float4 B0 = *(const float4*)&s_B  [n  * PAD_ + s * 8];
            float4 B1 = *(const float4*)&s_B  [n  * PAD_ + s * 8 + 4];
            float4 C0 = *(const float4*)&s_C  [n  * PAD_ + s * 8];
            float4 C1 = *(const float4*)&s_C  [n  * PAD_ + s * 8 + 4];
            float dv[8] = {d0.x, d0.y, d0.z, d0.w, d1.x, d1.y, d1.z, d1.w};
            float xv[8] = {x0.x, x0.y, x0.z, x0.w, x1.x, x1.y, x1.z, x1.w};
            float Bv[8] = {B0.x, B0.y, B0.z, B0.w, B1.x, B1.y, B1.z, B1.w};
            float Cv[8] = {C0.x, C0.y, C0.z, C0.w, C1.x, C1.y, C1.z, C1.w};
            #pragma unroll
            for (int jj = 0; jj < 8; jj++) {
                float a = __expf(dv[jj] * A);
                h = fmaf(a, h, (dv[jj] * xv[jj]) * Bv[jj]);
                float p = red16(h * Cv[jj]);
                if (n == 0) s_y[et * PAD_ + s * 8 + jj] = p + D * xv[jj];
            }
        }
        __syncthreads();
        // gated, coalesced chunk store
        #pragma unroll
        for (int j = 0; j < 4; j++) {
            int ll = lj + 16 * j;
            size_t row = rowbase + c * LC_ + ll;
            y[row * ED_ + e0 + le] = s_y[le * PAD_ + ll] * siluf(s_z[le * PAD_ + ll]);
        }
    }
}

// ---------------- final LN + head
__global__ void k_final(const float* __restrict__ x,
                        const float* __restrict__ fg, const float* __restrict__ fb,
                        const float* __restrict__ hw, const float* __restrict__ hb,
                        float* __restrict__ out) {
    __shared__ float sm[4];
    int row = blockIdx.x;
    int d = threadIdx.x;
    float v = x[row * DM_ + d];
    float mean = block_sum256(v, sm) * (1.0f / DM_);
    float dv = v - mean;
    float var = block_sum256(dv * dv, sm) * (1.0f / DM_);
    float rstd = rsqrtf(var + 1e-5f);
    float xf = dv * rstd * fg[d] + fb[d];
    float s0 = block_sum256(xf * hw[d * Q_ + 0], sm);
    float s1 = block_sum256(xf * hw[d * Q_ + 1], sm);
    if (d < Q_) {
        float s = (d == 0) ? s0 : s1;
        out[row * Q_ + d] = s + hb[d];
    }
}

extern "C" void kernel_launch(void* const* d_in, const int* in_sizes, int n_in,
                              void* d_out, int out_size, void* d_ws, size_t ws_size,
                              hipStream_t stream) {
    const int*   tokens    = (const int*)d_in[0];
    const float* T         = (const float*)d_in[1];
    const float* tok_embed = (const float*)d_in[2];
    const float* pos_embed = (const float*)d_in[3];
    const float* tw1       = (const float*)d_in[4];
    const float* tb1       = (const float*)d_in[5];
    const float* tw2       = (const float*)d_in[6];
    const float* tb2       = (const float*)d_in[7];
    const float* ag        = (const float*)d_in[8];
    const float* ab        = (const float*)d_in[9];
    const float* apw       = (const float*)d_in[10];
    const float* apb       = (const float*)d_in[11];
    const float* in_w      = (const float*)d_in[12];
    const float* conv_w    = (const float*)d_in[13];
    const float* conv_b    = (const float*)d_in[14];
    const float* xp_w      = (const float*)d_in[15];
    const float* dt_w      = (const float*)d_in[16];
    const float* dt_b      = (const float*)d_in[17];
    const float* A_log     = (const float*)d_in[18];
    const float* Dp        = (const float*)d_in[19];
    const float* out_w     = (const float*)d_in[20];
    const float* fg        = (const float*)d_in[21];
    const float* fb        = (const float*)d_in[22];
    const float* hw        = (const float*)d_in[23];
    const float* hb        = (const float*)d_in[24];
    float* out = (float*)d_out;

    float* ws = (float*)d_ws;
    const size_t N_X  = (size_t)B_ * L_ * DM_;
    const size_t N_XZ = (size_t)B_ * L_ * 2 * ED_;
    const size_t N_XS = (size_t)B_ * L_ * ED_;
    const size_t N_XD = (size_t)B_ * L_ * 48;
    float* x    = ws;                 size_t off = N_X;
    float* xn   = ws + off;           off += N_X;
    float* xz   = ws + off;           off += N_XZ;
    float* xs   = ws + off;           off += N_XS;
    float* xd   = ws + off;           off += N_XD;
    float* dlt  = ws + off;           off += N_XS;
    float* y    = dlt;                // alias: safe per k_scan chunk structure
    float* cond = ws + off;           off += B_ * CD_;
    float* ss   = ws + off;           off += B_ * 2 * DM_;

    const int ROWS = B_ * L_;   // 8192

    k_embed<<<ROWS, DM_, 0, stream>>>(tokens, tok_embed, pos_embed, x);
    k_cond<<<1, CD_, 0, stream>>>(T, tw1, tb1, tw2, tb2, cond);

    for (int i = 0; i < NL_; i++) {
        k_ss<<<B_, 2 * DM_, 0, stream>>>(cond, apw, apb, ss, i);
        k_lnmod<<<ROWS, DM_, 0, stream>>>(x, ag, ab, ss, xn, i);
        k_gemm<<<dim3(1024 / 64, ROWS / 64), 256, 0, stream>>>(
            xn, DM_, in_w + (size_t)i * DM_ * 2 * ED_, 2 * ED_,
            xz, 2 * ED_, ROWS, 2 * ED_, DM_, 0);
        k_conv<<<ROWS * ED_ / 256, 256, 0, stream>>>(xz, conv_w, conv_b, xs, i);
        k_gemm<<<dim3(1, ROWS / 64), 256, 0, stream>>>(
            xs, ED_, xp_w + (size_t)i * ED_ * (RK_ + 2 * NS_), RK_ + 2 * NS_,
            xd, RK_ + 2 * NS_, ROWS, RK_ + 2 * NS_, ED_, 0);
        k_dlt<<<ROWS * ED_ / 256, 256, 0, stream>>>(xd, dt_w, dt_b, dlt, i);
        k_scan<<<B_ * (ED_ / 16), 256, 0, stream>>>(
            dlt, xs, xd, xz, A_log, Dp, y, i);
        k_gemm<<<dim3(DM_ / 64, ROWS / 64), 256, 0, stream>>>(
            y, ED_, out_w + (size_t)i * ED_ * DM_, DM_,
            x, DM_, ROWS, DM_, ED_, 1);
    }

    k_final<<<ROWS, DM_, 0, stream>>>(x, fg, fb, hw, hb, out);
}

// Round 4
// 950.446 us; speedup vs baseline: 5.0091x; 1.9645x over previous
//
#include <hip/hip_runtime.h>
#include <hip/hip_bf16.h>
#include <math.h>

#define B_   8
#define L_   1024
#define DM_  256
#define NL_  4
#define ED_  512
#define NS_  16
#define DC_  4
#define RK_  16
#define CD_  64
#define Q_   2

#define LC_  64     // scan chunk length
#define PAD_ 68     // scan LDS row stride (floats)

typedef __hip_bfloat16 bf16_t;
typedef __attribute__((ext_vector_type(8))) short short8;
typedef __attribute__((ext_vector_type(4))) float floatx4;

__device__ __forceinline__ float geluf(float x) {
    return 0.5f * x * (1.0f + erff(x * 0.70710678118654752f));
}
__device__ __forceinline__ float siluf(float x) {
    return x / (1.0f + __expf(-x));
}
__device__ __forceinline__ float softplusf(float x) {
    return (x > 20.0f) ? x : log1pf(expf(x));
}
__device__ __forceinline__ float b2f(bf16_t v) { return __bfloat162float(v); }

// butterfly sum over 16-lane groups
__device__ __forceinline__ float red16(float p) {
    p += __int_as_float(__builtin_amdgcn_mov_dpp(__float_as_int(p), 0xB1, 0xF, 0xF, true));   // xor1
    p += __int_as_float(__builtin_amdgcn_mov_dpp(__float_as_int(p), 0x4E, 0xF, 0xF, true));   // xor2
    p += __int_as_float(__builtin_amdgcn_ds_swizzle(__float_as_int(p), 0x101F));              // xor4
    p += __int_as_float(__builtin_amdgcn_mov_dpp(__float_as_int(p), 0x128, 0xF, 0xF, true));  // ror8 == xor8
    return p;
}

__device__ __forceinline__ float block_sum256(float v, float* sm) {
    int tid = threadIdx.x;
    #pragma unroll
    for (int off = 32; off > 0; off >>= 1) v += __shfl_down(v, off, 64);
    __syncthreads();
    if ((tid & 63) == 0) sm[tid >> 6] = v;
    __syncthreads();
    return sm[0] + sm[1] + sm[2] + sm[3];
}

// ---------------- weight transpose + bf16 convert: src fp32 [R][C] -> dst bf16 [C][R]
__global__ void k_transpose(const float* __restrict__ src, bf16_t* __restrict__ dst,
                            int R, int C) {
    __shared__ float t[32][33];
    int c0 = blockIdx.x * 32, r0 = blockIdx.y * 32;
    int tx = threadIdx.x & 31, ty = threadIdx.x >> 5;   // 32 x 8
    #pragma unroll
    for (int i = 0; i < 32; i += 8) {
        int r = r0 + ty + i, c = c0 + tx;
        t[ty + i][tx] = (r < R && c < C) ? src[(size_t)r * C + c] : 0.f;
    }
    __syncthreads();
    #pragma unroll
    for (int i = 0; i < 32; i += 8) {
        int c = c0 + ty + i, r = r0 + tx;
        if (c < C && r < R) dst[(size_t)c * R + r] = __float2bfloat16(t[tx][ty + i]);
    }
}

// ---------------- embed
__global__ void k_embed(const int* __restrict__ tokens,
                        const float* __restrict__ tok_embed,
                        const float* __restrict__ pos_embed,
                        float* __restrict__ x) {
    int row = blockIdx.x;
    int d = threadIdx.x;
    int b = row / L_, l = row % L_;
    float v = pos_embed[l * DM_ + d];
    if (l > 0) {
        int tok = tokens[b * L_ + l - 1];
        v += tok_embed[tok * DM_ + d];
    }
    x[row * DM_ + d] = v;
}

// ---------------- conditioning
__global__ void k_cond(const float* __restrict__ T,
                       const float* __restrict__ tw1, const float* __restrict__ tb1,
                       const float* __restrict__ tw2, const float* __restrict__ tb2,
                       float* __restrict__ cond) {
    __shared__ float hbuf[B_ * CD_];
    int c = threadIdx.x;
    for (int b = 0; b < B_; b++) {
        float t = T[b];
        hbuf[b * CD_ + c] = geluf(t * tw1[c] + tb1[c]);
    }
    __syncthreads();
    for (int b = 0; b < B_; b++) {
        float acc = tb2[c];
        for (int cc = 0; cc < CD_; cc++)
            acc += hbuf[b * CD_ + cc] * tw2[cc * CD_ + c];
        cond[b * CD_ + c] = acc;
    }
}

// ---------------- per-layer adaLN params
__global__ void k_ss(const float* __restrict__ cond,
                     const float* __restrict__ apw, const float* __restrict__ apb,
                     float* __restrict__ ss, int layer) {
    int b = blockIdx.x;
    int j = threadIdx.x;
    const float* w = apw + (size_t)layer * CD_ * 2 * DM_;
    float acc = apb[layer * 2 * DM_ + j];
    for (int c = 0; c < CD_; c++)
        acc += cond[b * CD_ + c] * w[c * 2 * DM_ + j];
    ss[b * 2 * DM_ + j] = acc;
}

// ---------------- LN + adaLN modulation -> bf16 xn
__global__ void k_lnmod(const float* __restrict__ x,
                        const float* __restrict__ ag, const float* __restrict__ ab,
                        const float* __restrict__ ss,
                        bf16_t* __restrict__ xn, int layer) {
    __shared__ float sm[4];
    int row = blockIdx.x;
    int d = threadIdx.x;
    int b = row / L_;
    float v = x[row * DM_ + d];
    float mean = block_sum256(v, sm) * (1.0f / DM_);
    float dv = v - mean;
    float var = block_sum256(dv * dv, sm) * (1.0f / DM_);
    float rstd = rsqrtf(var + 1e-5f);
    float ln = dv * rstd * ag[layer * DM_ + d] + ab[layer * DM_ + d];
    float sc = ss[b * 2 * DM_ + d];
    float sh = ss[b * 2 * DM_ + DM_ + d];
    xn[row * DM_ + d] = __float2bfloat16((1.0f + sc) * ln + sh);
}

// ---------------- MFMA bf16 GEMM: C[M,N] (+)= A[M,K] @ Bt[N,K]^T
// 256 threads = 2x2 waves; per wave (BM/2)x(BN/2) via 16x16x32 MFMA tiles.
template<int BM, int BN, bool OUT_BF16, bool ACCUM>
__global__ __launch_bounds__(256) void k_mfma_gemm(
        const bf16_t* __restrict__ A, const bf16_t* __restrict__ Bt,
        float* __restrict__ Cf, bf16_t* __restrict__ Cb,
        int M, int N, int K) {
    constexpr int TM = BM / 32, TN = BN / 32;
    constexpr int NA = BM * 4 / 256;   // short8 vectors per thread for A tile (BM*32/8/256)
    constexpr int NB = BN * 4 / 256;
    __shared__ __align__(16) unsigned short sA[BM * 40];
    __shared__ __align__(16) unsigned short sB[BN * 40];

    const int tid = threadIdx.x;
    const int wave = tid >> 6, lane = tid & 63;
    const int lrow = lane & 15, lq = lane >> 4;
    const int row0 = blockIdx.y * BM, col0 = blockIdx.x * BN;
    const int wm0 = (wave >> 1) * (BM / 2);
    const int wn0 = (wave & 1) * (BN / 2);

    floatx4 acc[TM][TN];
    #pragma unroll
    for (int i = 0; i < TM; i++)
        #pragma unroll
        for (int j = 0; j < TN; j++) acc[i][j] = (floatx4)0.0f;

    short8 ra[NA], rb[NB];
    const int NKB = K / 32;

    // prologue loads (kb = 0)
    #pragma unroll
    for (int i = 0; i < NA; i++) {
        int vid = tid + i * 256; int m = vid >> 2, ko = (vid & 3) * 8;
        ra[i] = *(const short8*)(A + (size_t)(row0 + m) * K + ko);
    }
    #pragma unroll
    for (int i = 0; i < NB; i++) {
        int vid = tid + i * 256; int n = vid >> 2, ko = (vid & 3) * 8;
        int gn = col0 + n;
        rb[i] = (gn < N) ? *(const short8*)(Bt + (size_t)gn * K + ko) : (short8)0;
    }

    for (int kb = 0; kb < NKB; kb++) {
        __syncthreads();
        #pragma unroll
        for (int i = 0; i < NA; i++) {
            int vid = tid + i * 256; int m = vid >> 2, ko = (vid & 3) * 8;
            *(short8*)&sA[m * 40 + ko] = ra[i];
        }
        #pragma unroll
        for (int i = 0; i < NB; i++) {
            int vid = tid + i * 256; int n = vid >> 2, ko = (vid & 3) * 8;
            *(short8*)&sB[n * 40 + ko] = rb[i];
        }
        __syncthreads();
        if (kb + 1 < NKB) {
            int k0 = (kb + 1) * 32;
            #pragma unroll
            for (int i = 0; i < NA; i++) {
                int vid = tid + i * 256; int m = vid >> 2, ko = (vid & 3) * 8;
                ra[i] = *(const short8*)(A + (size_t)(row0 + m) * K + k0 + ko);
            }
            #pragma unroll
            for (int i = 0; i < NB; i++) {
                int vid = tid + i * 256; int n = vid >> 2, ko = (vid & 3) * 8;
                int gn = col0 + n;
                rb[i] = (gn < N) ? *(const short8*)(Bt + (size_t)gn * K + k0 + ko) : (short8)0;
            }
        }
        short8 af[TM], bfr[TN];
        #pragma unroll
        for (int i = 0; i < TM; i++)
            af[i] = *(const short8*)&sA[(wm0 + i * 16 + lrow) * 40 + lq * 8];
        #pragma unroll
        for (int j = 0; j < TN; j++)
            bfr[j] = *(const short8*)&sB[(wn0 + j * 16 + lrow) * 40 + lq * 8];
        #pragma unroll
        for (int i = 0; i < TM; i++)
            #pragma unroll
            for (int j = 0; j < TN; j++)
                acc[i][j] = __builtin_amdgcn_mfma_f32_16x16x32_bf16(af[i], bfr[j], acc[i][j], 0, 0, 0);
    }

    // epilogue: C/D layout col=lane&15, row=(lane>>4)*4+r
    #pragma unroll
    for (int i = 0; i < TM; i++) {
        int gr0 = row0 + wm0 + i * 16 + lq * 4;
        #pragma unroll
        for (int j = 0; j < TN; j++) {
            int gc = col0 + wn0 + j * 16 + lrow;
            if (gc < N) {
                #pragma unroll
                for (int r = 0; r < 4; r++) {
                    size_t idx = (size_t)(gr0 + r) * N + gc;
                    if (OUT_BF16)      Cb[idx] = __float2bfloat16(acc[i][j][r]);
                    else if (ACCUM)    Cf[idx] += acc[i][j][r];
                    else               Cf[idx] = acc[i][j][r];
                }
            }
        }
    }
}

// ---------------- causal depthwise conv (DC=4) + SiLU: bf16 in/out
__global__ void k_conv(const bf16_t* __restrict__ xz,
                       const float* __restrict__ conv_w, const float* __restrict__ conv_b,
                       bf16_t* __restrict__ xs, int layer) {
    int t = blockIdx.x * blockDim.x + threadIdx.x;
    int e = t % ED_;
    int row = t / ED_;
    int b = row / L_, l = row % L_;
    float acc = conv_b[layer * ED_ + e];
    const float* w = conv_w + ((size_t)layer * ED_ + e) * DC_;
    #pragma unroll
    for (int k = 0; k < DC_; k++) {
        int ll = l - (DC_ - 1) + k;
        if (ll >= 0)
            acc += b2f(xz[((size_t)(b * L_ + ll)) * (2 * ED_) + e]) * w[k];
    }
    xs[(size_t)row * ED_ + e] = __float2bfloat16(siluf(acc));
}

// ---------------- dlt = softplus(xd[:,:16] @ dt_w + dt_b) -> bf16
__global__ void k_dlt(const float* __restrict__ xd,
                      const float* __restrict__ dt_w, const float* __restrict__ dt_b,
                      bf16_t* __restrict__ dlt, int layer) {
    int t = blockIdx.x * blockDim.x + threadIdx.x;
    int e = t % ED_;
    int row = t / ED_;
    float acc = dt_b[layer * ED_ + e];
    const float* w = dt_w + (size_t)layer * RK_ * ED_;
    #pragma unroll
    for (int r = 0; r < RK_; r++)
        acc += xd[(size_t)row * (RK_ + 2 * NS_) + r] * w[r * ED_ + e];
    dlt[(size_t)row * ED_ + e] = __float2bfloat16(softplusf(acc));
}

// ---------------- selective scan, LDS-chunked, register-prefetched (bf16 I/O).
// y aliases dlt (bf16): chunk-c stores rows [c*LC,(c+1)*LC); prefetch reads beyond -> disjoint.
__global__ __launch_bounds__(256) void k_scan(
        const bf16_t* dlt, const bf16_t* __restrict__ xs,
        const float* __restrict__ xd,    // Bm at +16, Cm at +32 (row stride 48)
        const bf16_t* __restrict__ xz,   // z at +ED
        const float* __restrict__ A_log, const float* __restrict__ Dp,
        bf16_t* y, int layer) {
    __shared__ float s_dlt[16 * PAD_];
    __shared__ float s_xs [16 * PAD_];
    __shared__ float s_B  [16 * PAD_];
    __shared__ float s_C  [16 * PAD_];
    __shared__ float s_z  [16 * PAD_];
    __shared__ float s_y  [16 * PAD_];

    const int tid = threadIdx.x;
    const int n  = tid & 15;
    const int et = tid >> 4;
    const int b  = blockIdx.x >> 5;
    const int e0 = (blockIdx.x & 31) << 4;
    const int e  = e0 + et;

    const float A = -__expf(A_log[((size_t)layer * ED_ + e) * NS_ + n]);
    const float D = Dp[layer * ED_ + e];

    const int le = tid & 15;
    const int lj = tid >> 4;
    const int rowbase = b * L_;

    float r_d[4], r_x[4], r_B[4], r_C[4], r_z[4];
    #pragma unroll
    for (int j = 0; j < 4; j++) {
        size_t row = rowbase + lj + 16 * j;
        r_d[j] = b2f(dlt[row * ED_ + e0 + le]);
        r_x[j] = b2f(xs [row * ED_ + e0 + le]);
        r_B[j] = xd [row * 48 + 16 + le];
        r_C[j] = xd [row * 48 + 32 + le];
        r_z[j] = b2f(xz [row * (2 * ED_) + ED_ + e0 + le]);
    }

    float h = 0.0f;
    for (int c = 0; c < L_ / LC_; c++) {
        __syncthreads();
        #pragma unroll
        for (int j = 0; j < 4; j++) {
            int ll = lj + 16 * j;
            s_dlt[le * PAD_ + ll] = r_d[j];
            s_xs [le * PAD_ + ll] = r_x[j];
            s_B  [le * PAD_ + ll] = r_B[j];
            s_C  [le * PAD_ + ll] = r_C[j];
            s_z  [le * PAD_ + ll] = r_z[j];
        }
        __syncthreads();
        if (c + 1 < L_ / LC_) {
            #pragma unroll
            for (int j = 0; j < 4; j++) {
                size_t row = rowbase + (c + 1) * LC_ + lj + 16 * j;
                r_d[j] = b2f(dlt[row * ED_ + e0 + le]);
                r_x[j] = b2f(xs [row * ED_ + e0 + le]);
                r_B[j] = xd [row * 48 + 16 + le];
                r_C[j] = xd [row * 48 + 32 + le];
                r_z[j] = b2f(xz [row * (2 * ED_) + ED_ + e0 + le]);
            }
        }
        #pragma unroll
        for (int s = 0; s < LC_ / 8; s++) {
            float4 d0 = *(const float4*)&s_dlt[et * PAD_ + s * 8];
            float4 d1 = *(const float4*)&s_dlt[et * PAD_ + s * 8 + 4];
            float4 x0 = *(const float4*)&s_xs [et * PAD_ + s * 8];
            float4 x1 = *(const float4*)&s_xs [et * PAD_ + s * 8 + 4];
            float4 B0 = *(const float4*)&s_B  [n  * PAD_ + s * 8];
            float4 B1 = *(const float4*)&s_B  [n  * PAD_ + s * 8 + 4];
            float4 C0 = *(const float4*)&s_C  [n  * PAD_ + s * 8];
            float4 C1 = *(const float4*)&s_C  [n  * PAD_ + s * 8 + 4];
            float dv[8] = {d0.x, d0.y, d0.z, d0.w, d1.x, d1.y, d1.z, d1.w};
            float xv[8] = {x0.x, x0.y, x0.z, x0.w, x1.x, x1.y, x1.z, x1.w};
            float Bv[8] = {B0.x, B0.y, B0.z, B0.w, B1.x, B1.y, B1.z, B1.w};
            float Cv[8] = {C0.x, C0.y, C0.z, C0.w, C1.x, C1.y, C1.z, C1.w};
            #pragma unroll
            for (int jj = 0; jj < 8; jj++) {
                float a = __expf(dv[jj] * A);
                h = fmaf(a, h, (dv[jj] * xv[jj]) * Bv[jj]);
                float p = red16(h * Cv[jj]);
                if (n == 0) s_y[et * PAD_ + s * 8 + jj] = p + D * xv[jj];
            }
        }
        __syncthreads();
        #pragma unroll
        for (int j = 0; j < 4; j++) {
            int ll = lj + 16 * j;
            size_t row = rowbase + c * LC_ + ll;
            y[row * ED_ + e0 + le] =
                __float2bfloat16(s_y[le * PAD_ + ll] * siluf(s_z[le * PAD_ + ll]));
        }
    }
}

// ---------------- final LN + head
__global__ void k_final(const float* __restrict__ x,
                        const float* __restrict__ fg, const float* __restrict__ fb,
                        const float* __restrict__ hw, const float* __restrict__ hb,
                        float* __restrict__ out) {
    __shared__ float sm[4];
    int row = blockIdx.x;
    int d = threadIdx.x;
    float v = x[row * DM_ + d];
    float mean = block_sum256(v, sm) * (1.0f / DM_);
    float dv = v - mean;
    float var = block_sum256(dv * dv, sm) * (1.0f / DM_);
    float rstd = rsqrtf(var + 1e-5f);
    float xf = dv * rstd * fg[d] + fb[d];
    float s0 = block_sum256(xf * hw[d * Q_ + 0], sm);
    float s1 = block_sum256(xf * hw[d * Q_ + 1], sm);
    if (d < Q_) {
        float s = (d == 0) ? s0 : s1;
        out[row * Q_ + d] = s + hb[d];
    }
}

extern "C" void kernel_launch(void* const* d_in, const int* in_sizes, int n_in,
                              void* d_out, int out_size, void* d_ws, size_t ws_size,
                              hipStream_t stream) {
    const int*   tokens    = (const int*)d_in[0];
    const float* T         = (const float*)d_in[1];
    const float* tok_embed = (const float*)d_in[2];
    const float* pos_embed = (const float*)d_in[3];
    const float* tw1       = (const float*)d_in[4];
    const float* tb1       = (const float*)d_in[5];
    const float* tw2       = (const float*)d_in[6];
    const float* tb2       = (const float*)d_in[7];
    const float* ag        = (const float*)d_in[8];
    const float* ab        = (const float*)d_in[9];
    const float* apw       = (const float*)d_in[10];
    const float* apb       = (const float*)d_in[11];
    const float* in_w      = (const float*)d_in[12];
    const float* conv_w    = (const float*)d_in[13];
    const float* conv_b    = (const float*)d_in[14];
    const float* xp_w      = (const float*)d_in[15];
    const float* dt_w      = (const float*)d_in[16];
    const float* dt_b      = (const float*)d_in[17];
    const float* A_log     = (const float*)d_in[18];
    const float* Dp        = (const float*)d_in[19];
    const float* out_w     = (const float*)d_in[20];
    const float* fg        = (const float*)d_in[21];
    const float* fb        = (const float*)d_in[22];
    const float* hw        = (const float*)d_in[23];
    const float* hb        = (const float*)d_in[24];
    float* out = (float*)d_out;

    const int ROWS = B_ * L_;   // 8192

    char* p = (char*)d_ws;
    float*  x     = (float*)p;   p += (size_t)ROWS * DM_ * 4;
    bf16_t* xn    = (bf16_t*)p;  p += (size_t)ROWS * DM_ * 2;
    bf16_t* xz    = (bf16_t*)p;  p += (size_t)ROWS * 2 * ED_ * 2;
    bf16_t* xs    = (bf16_t*)p;  p += (size_t)ROWS * ED_ * 2;
    float*  xd    = (float*)p;   p += (size_t)ROWS * 48 * 4;
    bf16_t* dlt   = (bf16_t*)p;  p += (size_t)ROWS * ED_ * 2;
    bf16_t* y     = dlt;         // alias, safe per k_scan chunking
    float*  cond  = (float*)p;   p += B_ * CD_ * 4;
    float*  ss    = (float*)p;   p += B_ * 2 * DM_ * 4;
    bf16_t* in_wT = (bf16_t*)p;  p += (size_t)NL_ * 2 * ED_ * DM_ * 2;   // [1024][256] per layer
    bf16_t* xp_wT = (bf16_t*)p;  p += (size_t)NL_ * 48 * ED_ * 2;        // [48][512]
    bf16_t* out_wT= (bf16_t*)p;  p += (size_t)NL_ * DM_ * ED_ * 2;       // [256][512]

    // ---- one-time weight transposes (bf16, [N][K])
    for (int i = 0; i < NL_; i++) {
        k_transpose<<<dim3((2 * ED_ + 31) / 32, (DM_ + 31) / 32), 256, 0, stream>>>(
            in_w + (size_t)i * DM_ * 2 * ED_, in_wT + (size_t)i * 2 * ED_ * DM_, DM_, 2 * ED_);
        k_transpose<<<dim3((48 + 31) / 32, (ED_ + 31) / 32), 256, 0, stream>>>(
            xp_w + (size_t)i * ED_ * 48, xp_wT + (size_t)i * 48 * ED_, ED_, 48);
        k_transpose<<<dim3((DM_ + 31) / 32, (ED_ + 31) / 32), 256, 0, stream>>>(
            out_w + (size_t)i * ED_ * DM_, out_wT + (size_t)i * DM_ * ED_, ED_, DM_);
    }

    k_embed<<<ROWS, DM_, 0, stream>>>(tokens, tok_embed, pos_embed, x);
    k_cond<<<1, CD_, 0, stream>>>(T, tw1, tb1, tw2, tb2, cond);

    for (int i = 0; i < NL_; i++) {
        k_ss<<<B_, 2 * DM_, 0, stream>>>(cond, apw, apb, ss, i);
        k_lnmod<<<ROWS, DM_, 0, stream>>>(x, ag, ab, ss, xn, i);
        // xz = xn @ in_w[i]   (8192 x 256 x 1024), bf16 out
        k_mfma_gemm<128, 128, true, false><<<dim3(2 * ED_ / 128, ROWS / 128), 256, 0, stream>>>(
            xn, in_wT + (size_t)i * 2 * ED_ * DM_, nullptr, xz, ROWS, 2 * ED_, DM_);
        k_conv<<<ROWS * ED_ / 256, 256, 0, stream>>>(xz, conv_w, conv_b, xs, i);
        // xd = xs @ xp_w[i]   (8192 x 512 x 48), fp32 out
        k_mfma_gemm<64, 64, false, false><<<dim3(1, ROWS / 64), 256, 0, stream>>>(
            xs, xp_wT + (size_t)i * 48 * ED_, xd, nullptr, ROWS, 48, ED_);
        k_dlt<<<ROWS * ED_ / 256, 256, 0, stream>>>(xd, dt_w, dt_b, dlt, i);
        k_scan<<<B_ * (ED_ / 16), 256, 0, stream>>>(
            dlt, xs, xd, xz, A_log, Dp, y, i);
        // x += y @ out_w[i]   (8192 x 512 x 256), fp32 accumulate
        k_mfma_gemm<128, 64, false, true><<<dim3(DM_ / 64, ROWS / 128), 256, 0, stream>>>(
            y, out_wT + (size_t)i * DM_ * ED_, x, nullptr, ROWS, DM_, ED_);
    }

    k_final<<<ROWS, DM_, 0, stream>>>(x, fg, fb, hw, hb, out);
}

// Round 5
// 713.816 us; speedup vs baseline: 6.6696x; 1.3315x over previous
//
#include <hip/hip_runtime.h>
#include <hip/hip_bf16.h>
#include <math.h>

#define B_   8
#define L_   1024
#define DM_  256
#define NL_  4
#define ED_  512
#define NS_  16
#define DC_  4
#define RK_  16
#define CD_  64
#define Q_   2

#define LC_   64    // scan chunk length (LDS staging)
#define PAD_  68    // scan LDS row stride (floats)
#define SEG_  8     // segments along L for chunked scan
#define SLEN_ 128   // L_/SEG_

typedef __hip_bfloat16 bf16_t;
typedef __attribute__((ext_vector_type(8))) short short8;
typedef __attribute__((ext_vector_type(4))) float floatx4;

__device__ __forceinline__ float geluf(float x) {
    return 0.5f * x * (1.0f + erff(x * 0.70710678118654752f));
}
__device__ __forceinline__ float siluf(float x) {
    return x / (1.0f + __expf(-x));
}
__device__ __forceinline__ float softplusf(float x) {
    return (x > 20.0f) ? x : log1pf(expf(x));
}
__device__ __forceinline__ float b2f(bf16_t v) { return __bfloat162float(v); }

// butterfly sum over 16-lane groups
__device__ __forceinline__ float red16(float p) {
    p += __int_as_float(__builtin_amdgcn_mov_dpp(__float_as_int(p), 0xB1, 0xF, 0xF, true));   // xor1
    p += __int_as_float(__builtin_amdgcn_mov_dpp(__float_as_int(p), 0x4E, 0xF, 0xF, true));   // xor2
    p += __int_as_float(__builtin_amdgcn_ds_swizzle(__float_as_int(p), 0x101F));              // xor4
    p += __int_as_float(__builtin_amdgcn_mov_dpp(__float_as_int(p), 0x128, 0xF, 0xF, true));  // ror8 == xor8
    return p;
}

__device__ __forceinline__ float block_sum256(float v, float* sm) {
    int tid = threadIdx.x;
    #pragma unroll
    for (int off = 32; off > 0; off >>= 1) v += __shfl_down(v, off, 64);
    __syncthreads();
    if ((tid & 63) == 0) sm[tid >> 6] = v;
    __syncthreads();
    return sm[0] + sm[1] + sm[2] + sm[3];
}

// ---------------- batched weight transpose + bf16 convert: per layer z,
// src fp32 [R][C] -> dst bf16 [C][R]
__global__ void k_transpose(const float* __restrict__ src0, bf16_t* __restrict__ dst0,
                            int R, int C) {
    __shared__ float t[32][33];
    const float* src = src0 + (size_t)blockIdx.z * R * C;
    bf16_t* dst = dst0 + (size_t)blockIdx.z * R * C;
    int c0 = blockIdx.x * 32, r0 = blockIdx.y * 32;
    int tx = threadIdx.x & 31, ty = threadIdx.x >> 5;   // 32 x 8
    #pragma unroll
    for (int i = 0; i < 32; i += 8) {
        int r = r0 + ty + i, c = c0 + tx;
        t[ty + i][tx] = (r < R && c < C) ? src[(size_t)r * C + c] : 0.f;
    }
    __syncthreads();
    #pragma unroll
    for (int i = 0; i < 32; i += 8) {
        int c = c0 + ty + i, r = r0 + tx;
        if (c < C && r < R) dst[(size_t)c * R + r] = __float2bfloat16(t[tx][ty + i]);
    }
}

// ---------------- embed
__global__ void k_embed(const int* __restrict__ tokens,
                        const float* __restrict__ tok_embed,
                        const float* __restrict__ pos_embed,
                        float* __restrict__ x) {
    int row = blockIdx.x;
    int d = threadIdx.x;
    int b = row / L_, l = row % L_;
    float v = pos_embed[l * DM_ + d];
    if (l > 0) {
        int tok = tokens[b * L_ + l - 1];
        v += tok_embed[tok * DM_ + d];
    }
    x[row * DM_ + d] = v;
}

// ---------------- conditioning
__global__ void k_cond(const float* __restrict__ T,
                       const float* __restrict__ tw1, const float* __restrict__ tb1,
                       const float* __restrict__ tw2, const float* __restrict__ tb2,
                       float* __restrict__ cond) {
    __shared__ float hbuf[B_ * CD_];
    int c = threadIdx.x;
    for (int b = 0; b < B_; b++) {
        float t = T[b];
        hbuf[b * CD_ + c] = geluf(t * tw1[c] + tb1[c]);
    }
    __syncthreads();
    for (int b = 0; b < B_; b++) {
        float acc = tb2[c];
        for (int cc = 0; cc < CD_; cc++)
            acc += hbuf[b * CD_ + cc] * tw2[cc * CD_ + c];
        cond[b * CD_ + c] = acc;
    }
}

// ---------------- per-layer adaLN params
__global__ void k_ss(const float* __restrict__ cond,
                     const float* __restrict__ apw, const float* __restrict__ apb,
                     float* __restrict__ ss, int layer) {
    int b = blockIdx.x;
    int j = threadIdx.x;
    const float* w = apw + (size_t)layer * CD_ * 2 * DM_;
    float acc = apb[layer * 2 * DM_ + j];
    for (int c = 0; c < CD_; c++)
        acc += cond[b * CD_ + c] * w[c * 2 * DM_ + j];
    ss[b * 2 * DM_ + j] = acc;
}

// ---------------- LN + adaLN modulation -> bf16 xn
__global__ void k_lnmod(const float* __restrict__ x,
                        const float* __restrict__ ag, const float* __restrict__ ab,
                        const float* __restrict__ ss,
                        bf16_t* __restrict__ xn, int layer) {
    __shared__ float sm[4];
    int row = blockIdx.x;
    int d = threadIdx.x;
    int b = row / L_;
    float v = x[row * DM_ + d];
    float mean = block_sum256(v, sm) * (1.0f / DM_);
    float dv = v - mean;
    float var = block_sum256(dv * dv, sm) * (1.0f / DM_);
    float rstd = rsqrtf(var + 1e-5f);
    float ln = dv * rstd * ag[layer * DM_ + d] + ab[layer * DM_ + d];
    float sc = ss[b * 2 * DM_ + d];
    float sh = ss[b * 2 * DM_ + DM_ + d];
    xn[row * DM_ + d] = __float2bfloat16((1.0f + sc) * ln + sh);
}

// ---------------- MFMA bf16 GEMM: C[M,N] (+)= A[M,K] @ Bt[N,K]^T
template<int BM, int BN, bool OUT_BF16, bool ACCUM>
__global__ __launch_bounds__(256) void k_mfma_gemm(
        const bf16_t* __restrict__ A, const bf16_t* __restrict__ Bt,
        float* __restrict__ Cf, bf16_t* __restrict__ Cb,
        int M, int N, int K) {
    constexpr int TM = BM / 32, TN = BN / 32;
    constexpr int NA = BM * 4 / 256;
    constexpr int NB = BN * 4 / 256;
    __shared__ __align__(16) unsigned short sA[BM * 40];
    __shared__ __align__(16) unsigned short sB[BN * 40];

    const int tid = threadIdx.x;
    const int wave = tid >> 6, lane = tid & 63;
    const int lrow = lane & 15, lq = lane >> 4;
    const int row0 = blockIdx.y * BM, col0 = blockIdx.x * BN;
    const int wm0 = (wave >> 1) * (BM / 2);
    const int wn0 = (wave & 1) * (BN / 2);

    floatx4 acc[TM][TN];
    #pragma unroll
    for (int i = 0; i < TM; i++)
        #pragma unroll
        for (int j = 0; j < TN; j++) acc[i][j] = (floatx4)0.0f;

    short8 ra[NA], rb[NB];
    const int NKB = K / 32;

    #pragma unroll
    for (int i = 0; i < NA; i++) {
        int vid = tid + i * 256; int m = vid >> 2, ko = (vid & 3) * 8;
        ra[i] = *(const short8*)(A + (size_t)(row0 + m) * K + ko);
    }
    #pragma unroll
    for (int i = 0; i < NB; i++) {
        int vid = tid + i * 256; int n = vid >> 2, ko = (vid & 3) * 8;
        int gn = col0 + n;
        rb[i] = (gn < N) ? *(const short8*)(Bt + (size_t)gn * K + ko) : (short8)0;
    }

    for (int kb = 0; kb < NKB; kb++) {
        __syncthreads();
        #pragma unroll
        for (int i = 0; i < NA; i++) {
            int vid = tid + i * 256; int m = vid >> 2, ko = (vid & 3) * 8;
            *(short8*)&sA[m * 40 + ko] = ra[i];
        }
        #pragma unroll
        for (int i = 0; i < NB; i++) {
            int vid = tid + i * 256; int n = vid >> 2, ko = (vid & 3) * 8;
            *(short8*)&sB[n * 40 + ko] = rb[i];
        }
        __syncthreads();
        if (kb + 1 < NKB) {
            int k0 = (kb + 1) * 32;
            #pragma unroll
            for (int i = 0; i < NA; i++) {
                int vid = tid + i * 256; int m = vid >> 2, ko = (vid & 3) * 8;
                ra[i] = *(const short8*)(A + (size_t)(row0 + m) * K + k0 + ko);
            }
            #pragma unroll
            for (int i = 0; i < NB; i++) {
                int vid = tid + i * 256; int n = vid >> 2, ko = (vid & 3) * 8;
                int gn = col0 + n;
                rb[i] = (gn < N) ? *(const short8*)(Bt + (size_t)gn * K + k0 + ko) : (short8)0;
            }
        }
        short8 af[TM], bfr[TN];
        #pragma unroll
        for (int i = 0; i < TM; i++)
            af[i] = *(const short8*)&sA[(wm0 + i * 16 + lrow) * 40 + lq * 8];
        #pragma unroll
        for (int j = 0; j < TN; j++)
            bfr[j] = *(const short8*)&sB[(wn0 + j * 16 + lrow) * 40 + lq * 8];
        #pragma unroll
        for (int i = 0; i < TM; i++)
            #pragma unroll
            for (int j = 0; j < TN; j++)
                acc[i][j] = __builtin_amdgcn_mfma_f32_16x16x32_bf16(af[i], bfr[j], acc[i][j], 0, 0, 0);
    }

    #pragma unroll
    for (int i = 0; i < TM; i++) {
        int gr0 = row0 + wm0 + i * 16 + lq * 4;
        #pragma unroll
        for (int j = 0; j < TN; j++) {
            int gc = col0 + wn0 + j * 16 + lrow;
            if (gc < N) {
                #pragma unroll
                for (int r = 0; r < 4; r++) {
                    size_t idx = (size_t)(gr0 + r) * N + gc;
                    if (OUT_BF16)      Cb[idx] = __float2bfloat16(acc[i][j][r]);
                    else if (ACCUM)    Cf[idx] += acc[i][j][r];
                    else               Cf[idx] = acc[i][j][r];
                }
            }
        }
    }
}

// ---------------- causal depthwise conv (DC=4) + SiLU: bf16 in/out, 2 e per thread
__global__ void k_conv(const bf16_t* __restrict__ xz,
                       const float* __restrict__ conv_w, const float* __restrict__ conv_b,
                       bf16_t* __restrict__ xs, int layer) {
    int t = blockIdx.x * blockDim.x + threadIdx.x;   // ROWS * ED/2
    int ep = t % (ED_ / 2);
    int row = t / (ED_ / 2);
    int e = ep * 2;
    int b = row / L_, l = row % L_;
    float4 w0 = *(const float4*)(conv_w + ((size_t)layer * ED_ + e) * DC_);
    float4 w1 = *(const float4*)(conv_w + ((size_t)layer * ED_ + e + 1) * DC_);
    float acc0 = conv_b[layer * ED_ + e];
    float acc1 = conv_b[layer * ED_ + e + 1];
    const float wa0[4] = {w0.x, w0.y, w0.z, w0.w};
    const float wa1[4] = {w1.x, w1.y, w1.z, w1.w};
    #pragma unroll
    for (int k = 0; k < DC_; k++) {
        int ll = l - (DC_ - 1) + k;
        if (ll >= 0) {
            __hip_bfloat162 v = *(const __hip_bfloat162*)(xz + ((size_t)(b * L_ + ll)) * (2 * ED_) + e);
            acc0 += b2f(v.x) * wa0[k];
            acc1 += b2f(v.y) * wa1[k];
        }
    }
    __hip_bfloat162 o;
    o.x = __float2bfloat16(siluf(acc0));
    o.y = __float2bfloat16(siluf(acc1));
    *(__hip_bfloat162*)(xs + (size_t)row * ED_ + e) = o;
}

// ---------------- dlt = softplus(xd[:,:16] @ dt_w + dt_b) -> bf16
__global__ void k_dlt(const float* __restrict__ xd,
                      const float* __restrict__ dt_w, const float* __restrict__ dt_b,
                      bf16_t* __restrict__ dlt, int layer) {
    int t = blockIdx.x * blockDim.x + threadIdx.x;
    int e = t % ED_;
    int row = t / ED_;
    float acc = dt_b[layer * ED_ + e];
    const float* w = dt_w + (size_t)layer * RK_ * ED_;
    #pragma unroll
    for (int r = 0; r < RK_; r++)
        acc += xd[(size_t)row * (RK_ + 2 * NS_) + r] * w[r * ED_ + e];
    dlt[(size_t)row * ED_ + e] = __float2bfloat16(softplusf(acc));
}

// ======== chunked selective scan: 3 phases over SEG_=8 segments of 128 steps ====
// state buffers indexed [(b*32+etile)*SEG + seg]*256 + tid, tid = et*16+n

// phase 1: local recurrence from h=0; emit P = prod(a), h_end
__global__ __launch_bounds__(256) void k_scan1(
        const bf16_t* __restrict__ dlt, const bf16_t* __restrict__ xs,
        const float* __restrict__ xd,    // Bm at +16 (row stride 48)
        const float* __restrict__ A_log,
        float* __restrict__ aprod, float* __restrict__ hend, int layer) {
    __shared__ float s_dlt[16 * PAD_];
    __shared__ float s_xs [16 * PAD_];
    __shared__ float s_B  [16 * PAD_];

    const int tid = threadIdx.x;
    const int n  = tid & 15;
    const int et = tid >> 4;
    const int bi = blockIdx.x;
    const int seg = bi & (SEG_ - 1);
    const int etile = (bi >> 3) & 31;
    const int b = bi >> 8;
    const int e0 = etile << 4;
    const int e  = e0 + et;

    const float A = -__expf(A_log[((size_t)layer * ED_ + e) * NS_ + n]);

    const int le = tid & 15;
    const int lj = tid >> 4;
    const int rowbase = b * L_ + seg * SLEN_;

    float r_d[4], r_x[4], r_B[4];
    #pragma unroll
    for (int j = 0; j < 4; j++) {
        size_t row = rowbase + lj + 16 * j;
        r_d[j] = b2f(dlt[row * ED_ + e0 + le]);
        r_x[j] = b2f(xs [row * ED_ + e0 + le]);
        r_B[j] = xd [row * 48 + 16 + le];
    }

    float h = 0.0f, P = 1.0f;
    #pragma unroll
    for (int c = 0; c < SLEN_ / LC_; c++) {
        __syncthreads();
        #pragma unroll
        for (int j = 0; j < 4; j++) {
            int ll = lj + 16 * j;
            s_dlt[le * PAD_ + ll] = r_d[j];
            s_xs [le * PAD_ + ll] = r_x[j];
            s_B  [le * PAD_ + ll] = r_B[j];
        }
        __syncthreads();
        if (c + 1 < SLEN_ / LC_) {
            #pragma unroll
            for (int j = 0; j < 4; j++) {
                size_t row = rowbase + (c + 1) * LC_ + lj + 16 * j;
                r_d[j] = b2f(dlt[row * ED_ + e0 + le]);
                r_x[j] = b2f(xs [row * ED_ + e0 + le]);
                r_B[j] = xd [row * 48 + 16 + le];
            }
        }
        #pragma unroll
        for (int s = 0; s < LC_ / 8; s++) {
            float4 d0 = *(const float4*)&s_dlt[et * PAD_ + s * 8];
            float4 d1 = *(const float4*)&s_dlt[et * PAD_ + s * 8 + 4];
            float4 x0 = *(const float4*)&s_xs [et * PAD_ + s * 8];
            float4 x1 = *(const float4*)&s_xs [et * PAD_ + s * 8 + 4];
            float4 B0 = *(const float4*)&s_B  [n  * PAD_ + s * 8];
            float4 B1 = *(const float4*)&s_B  [n  * PAD_ + s * 8 + 4];
            float dv[8] = {d0.x, d0.y, d0.z, d0.w, d1.x, d1.y, d1.z, d1.w};
            float xv[8] = {x0.x, x0.y, x0.z, x0.w, x1.x, x1.y, x1.z, x1.w};
            float Bv[8] = {B0.x, B0.y, B0.z, B0.w, B1.x, B1.y, B1.z, B1.w};
            #pragma unroll
            for (int jj = 0; jj < 8; jj++) {
                float a = __expf(dv[jj] * A);
                h = fmaf(a, h, (dv[jj] * xv[jj]) * Bv[jj]);
                P *= a;
            }
        }
    }
    size_t idx = (((size_t)(b * 32 + etile) * SEG_ + seg) << 8) + tid;
    aprod[idx] = P;
    hend[idx]  = h;
}

// phase 2: sequential stitch across segments -> H_in per segment
__global__ void k_scan2(const float* __restrict__ aprod, const float* __restrict__ hend,
                        float* __restrict__ hin) {
    int tid = threadIdx.x;
    size_t bi = blockIdx.x;          // b*32 + etile
    float H = 0.f;
    #pragma unroll
    for (int s = 0; s < SEG_; s++) {
        size_t idx = ((bi * SEG_ + s) << 8) + tid;
        hin[idx] = H;
        H = aprod[idx] * H + hend[idx];
    }
}

// phase 3: full scan seeded with H_in; reduction + D bypass + SiLU gate.
// y aliases dlt: block touches only its segment's rows; dlt reads (incl. prefetch)
// precede y stores for the same rows within the block; phases are stream-ordered.
__global__ __launch_bounds__(256) void k_scan3(
        const bf16_t* dlt, const bf16_t* __restrict__ xs,
        const float* __restrict__ xd,    // Bm at +16, Cm at +32 (row stride 48)
        const bf16_t* __restrict__ xz,   // z at +ED
        const float* __restrict__ A_log, const float* __restrict__ Dp,
        const float* __restrict__ hin,
        bf16_t* y, int layer) {
    __shared__ float s_dlt[16 * PAD_];
    __shared__ float s_xs [16 * PAD_];
    __shared__ float s_B  [16 * PAD_];
    __shared__ float s_C  [16 * PAD_];
    __shared__ float s_z  [16 * PAD_];
    __shared__ float s_y  [16 * PAD_];

    const int tid = threadIdx.x;
    const int n  = tid & 15;
    const int et = tid >> 4;
    const int bi = blockIdx.x;
    const int seg = bi & (SEG_ - 1);
    const int etile = (bi >> 3) & 31;
    const int b = bi >> 8;
    const int e0 = etile << 4;
    const int e  = e0 + et;

    const float A = -__expf(A_log[((size_t)layer * ED_ + e) * NS_ + n]);
    const float D = Dp[layer * ED_ + e];

    const int le = tid & 15;
    const int lj = tid >> 4;
    const int rowbase = b * L_ + seg * SLEN_;

    float r_d[4], r_x[4], r_B[4], r_C[4], r_z[4];
    #pragma unroll
    for (int j = 0; j < 4; j++) {
        size_t row = rowbase + lj + 16 * j;
        r_d[j] = b2f(dlt[row * ED_ + e0 + le]);
        r_x[j] = b2f(xs [row * ED_ + e0 + le]);
        r_B[j] = xd [row * 48 + 16 + le];
        r_C[j] = xd [row * 48 + 32 + le];
        r_z[j] = b2f(xz [row * (2 * ED_) + ED_ + e0 + le]);
    }

    float h = hin[(((size_t)(b * 32 + etile) * SEG_ + seg) << 8) + tid];

    #pragma unroll
    for (int c = 0; c < SLEN_ / LC_; c++) {
        __syncthreads();
        #pragma unroll
        for (int j = 0; j < 4; j++) {
            int ll = lj + 16 * j;
            s_dlt[le * PAD_ + ll] = r_d[j];
            s_xs [le * PAD_ + ll] = r_x[j];
            s_B  [le * PAD_ + ll] = r_B[j];
            s_C  [le * PAD_ + ll] = r_C[j];
            s_z  [le * PAD_ + ll] = r_z[j];
        }
        __syncthreads();
        if (c + 1 < SLEN_ / LC_) {
            #pragma unroll
            for (int j = 0; j < 4; j++) {
                size_t row = rowbase + (c + 1) * LC_ + lj + 16 * j;
                r_d[j] = b2f(dlt[row * ED_ + e0 + le]);
                r_x[j] = b2f(xs [row * ED_ + e0 + le]);
                r_B[j] = xd [row * 48 + 16 + le];
                r_C[j] = xd [row * 48 + 32 + le];
                r_z[j] = b2f(xz [row * (2 * ED_) + ED_ + e0 + le]);
            }
        }
        #pragma unroll
        for (int s = 0; s < LC_ / 8; s++) {
            float4 d0 = *(const float4*)&s_dlt[et * PAD_ + s * 8];
            float4 d1 = *(const float4*)&s_dlt[et * PAD_ + s * 8 + 4];
            float4 x0 = *(const float4*)&s_xs [et * PAD_ + s * 8];
            float4 x1 = *(const float4*)&s_xs [et * PAD_ + s * 8 + 4];
            float4 B0 = *(const float4*)&s_B  [n  * PAD_ + s * 8];
            float4 B1 = *(const float4*)&s_B  [n  * PAD_ + s * 8 + 4];
            float4 C0 = *(const float4*)&s_C  [n  * PAD_ + s * 8];
            float4 C1 = *(const float4*)&s_C  [n  * PAD_ + s * 8 + 4];
            float dv[8] = {d0.x, d0.y, d0.z, d0.w, d1.x, d1.y, d1.z, d1.w};
            float xv[8] = {x0.x, x0.y, x0.z, x0.w, x1.x, x1.y, x1.z, x1.w};
            float Bv[8] = {B0.x, B0.y, B0.z, B0.w, B1.x, B1.y, B1.z, B1.w};
            float Cv[8] = {C0.x, C0.y, C0.z, C0.w, C1.x, C1.y, C1.z, C1.w};
            #pragma unroll
            for (int jj = 0; jj < 8; jj++) {
                float a = __expf(dv[jj] * A);
                h = fmaf(a, h, (dv[jj] * xv[jj]) * Bv[jj]);
                float p = red16(h * Cv[jj]);
                if (n == 0) s_y[et * PAD_ + s * 8 + jj] = p + D * xv[jj];
            }
        }
        __syncthreads();
        #pragma unroll
        for (int j = 0; j < 4; j++) {
            int ll = lj + 16 * j;
            size_t row = rowbase + c * LC_ + ll;
            y[row * ED_ + e0 + le] =
                __float2bfloat16(s_y[le * PAD_ + ll] * siluf(s_z[le * PAD_ + ll]));
        }
    }
}

// ---------------- final LN + head
__global__ void k_final(const float* __restrict__ x,
                        const float* __restrict__ fg, const float* __restrict__ fb,
                        const float* __restrict__ hw, const float* __restrict__ hb,
                        float* __restrict__ out) {
    __shared__ float sm[4];
    int row = blockIdx.x;
    int d = threadIdx.x;
    float v = x[row * DM_ + d];
    float mean = block_sum256(v, sm) * (1.0f / DM_);
    float dv = v - mean;
    float var = block_sum256(dv * dv, sm) * (1.0f / DM_);
    float rstd = rsqrtf(var + 1e-5f);
    float xf = dv * rstd * fg[d] + fb[d];
    float s0 = block_sum256(xf * hw[d * Q_ + 0], sm);
    float s1 = block_sum256(xf * hw[d * Q_ + 1], sm);
    if (d < Q_) {
        float s = (d == 0) ? s0 : s1;
        out[row * Q_ + d] = s + hb[d];
    }
}

extern "C" void kernel_launch(void* const* d_in, const int* in_sizes, int n_in,
                              void* d_out, int out_size, void* d_ws, size_t ws_size,
                              hipStream_t stream) {
    const int*   tokens    = (const int*)d_in[0];
    const float* T         = (const float*)d_in[1];
    const float* tok_embed = (const float*)d_in[2];
    const float* pos_embed = (const float*)d_in[3];
    const float* tw1       = (const float*)d_in[4];
    const float* tb1       = (const float*)d_in[5];
    const float* tw2       = (const float*)d_in[6];
    const float* tb2       = (const float*)d_in[7];
    const float* ag        = (const float*)d_in[8];
    const float* ab        = (const float*)d_in[9];
    const float* apw       = (const float*)d_in[10];
    const float* apb       = (const float*)d_in[11];
    const float* in_w      = (const float*)d_in[12];
    const float* conv_w    = (const float*)d_in[13];
    const float* conv_b    = (const float*)d_in[14];
    const float* xp_w      = (const float*)d_in[15];
    const float* dt_w      = (const float*)d_in[16];
    const float* dt_b      = (const float*)d_in[17];
    const float* A_log     = (const float*)d_in[18];
    const float* Dp        = (const float*)d_in[19];
    const float* out_w     = (const float*)d_in[20];
    const float* fg        = (const float*)d_in[21];
    const float* fb        = (const float*)d_in[22];
    const float* hw        = (const float*)d_in[23];
    const float* hb        = (const float*)d_in[24];
    float* out = (float*)d_out;

    const int ROWS = B_ * L_;   // 8192

    char* p = (char*)d_ws;
    float*  x     = (float*)p;   p += (size_t)ROWS * DM_ * 4;
    bf16_t* xn    = (bf16_t*)p;  p += (size_t)ROWS * DM_ * 2;
    bf16_t* xz    = (bf16_t*)p;  p += (size_t)ROWS * 2 * ED_ * 2;
    bf16_t* xs    = (bf16_t*)p;  p += (size_t)ROWS * ED_ * 2;
    float*  xd    = (float*)p;   p += (size_t)ROWS * 48 * 4;
    bf16_t* dlt   = (bf16_t*)p;  p += (size_t)ROWS * ED_ * 2;
    bf16_t* y     = dlt;         // alias, safe per k_scan3 structure
    float*  cond  = (float*)p;   p += B_ * CD_ * 4;
    float*  ss    = (float*)p;   p += B_ * 2 * DM_ * 4;
    float*  aprod = (float*)p;   p += (size_t)B_ * ED_ * NS_ * SEG_ * 4;  // 2 MB
    float*  hend  = (float*)p;   p += (size_t)B_ * ED_ * NS_ * SEG_ * 4;  // 2 MB
    float*  hin   = (float*)p;   p += (size_t)B_ * ED_ * NS_ * SEG_ * 4;  // 2 MB
    bf16_t* in_wT = (bf16_t*)p;  p += (size_t)NL_ * 2 * ED_ * DM_ * 2;
    bf16_t* xp_wT = (bf16_t*)p;  p += (size_t)NL_ * 48 * ED_ * 2;
    bf16_t* out_wT= (bf16_t*)p;  p += (size_t)NL_ * DM_ * ED_ * 2;

    // ---- one-time weight transposes (bf16, [N][K]), batched over layers
    k_transpose<<<dim3(2 * ED_ / 32, DM_ / 32, NL_), 256, 0, stream>>>(in_w, in_wT, DM_, 2 * ED_);
    k_transpose<<<dim3((48 + 31) / 32, ED_ / 32, NL_), 256, 0, stream>>>(xp_w, xp_wT, ED_, 48);
    k_transpose<<<dim3(DM_ / 32, ED_ / 32, NL_), 256, 0, stream>>>(out_w, out_wT, ED_, DM_);

    k_embed<<<ROWS, DM_, 0, stream>>>(tokens, tok_embed, pos_embed, x);
    k_cond<<<1, CD_, 0, stream>>>(T, tw1, tb1, tw2, tb2, cond);

    for (int i = 0; i < NL_; i++) {
        k_ss<<<B_, 2 * DM_, 0, stream>>>(cond, apw, apb, ss, i);
        k_lnmod<<<ROWS, DM_, 0, stream>>>(x, ag, ab, ss, xn, i);
        // xz = xn @ in_w[i]   (8192 x 256 x 1024), bf16 out
        k_mfma_gemm<128, 128, true, false><<<dim3(2 * ED_ / 128, ROWS / 128), 256, 0, stream>>>(
            xn, in_wT + (size_t)i * 2 * ED_ * DM_, nullptr, xz, ROWS, 2 * ED_, DM_);
        k_conv<<<ROWS * (ED_ / 2) / 256, 256, 0, stream>>>(xz, conv_w, conv_b, xs, i);
        // xd = xs @ xp_w[i]   (8192 x 512 x 48), fp32 out
        k_mfma_gemm<64, 64, false, false><<<dim3(1, ROWS / 64), 256, 0, stream>>>(
            xs, xp_wT + (size_t)i * 48 * ED_, xd, nullptr, ROWS, 48, ED_);
        k_dlt<<<ROWS * ED_ / 256, 256, 0, stream>>>(xd, dt_w, dt_b, dlt, i);
        // chunked scan
        k_scan1<<<B_ * 32 * SEG_, 256, 0, stream>>>(dlt, xs, xd, A_log, aprod, hend, i);
        k_scan2<<<B_ * 32, 256, 0, stream>>>(aprod, hend, hin);
        k_scan3<<<B_ * 32 * SEG_, 256, 0, stream>>>(dlt, xs, xd, xz, A_log, Dp, hin, y, i);
        // x += y @ out_w[i]   (8192 x 512 x 256), fp32 accumulate
        k_mfma_gemm<128, 64, false, true><<<dim3(DM_ / 64, ROWS / 128), 256, 0, stream>>>(
            y, out_wT + (size_t)i * DM_ * ED_, x, nullptr, ROWS, DM_, ED_);
    }

    k_final<<<ROWS, DM_, 0, stream>>>(x, fg, fb, hw, hb, out);
}

// Round 6
// 697.709 us; speedup vs baseline: 6.8236x; 1.0231x over previous
//
#include <hip/hip_runtime.h>
#include <hip/hip_bf16.h>
#include <math.h>

#define B_   8
#define L_   1024
#define DM_  256
#define NL_  4
#define ED_  512
#define NS_  16
#define DC_  4
#define RK_  16
#define CD_  64
#define Q_   2

#define PAD_  68    // scan LDS row stride (floats)
#define SEG_  16    // segments along L for chunked scan
#define SLEN_ 64    // L_/SEG_  (== one LDS chunk)

typedef __hip_bfloat16 bf16_t;
typedef __attribute__((ext_vector_type(8))) short short8;
typedef __attribute__((ext_vector_type(4))) float floatx4;

__device__ __forceinline__ float geluf(float x) {
    return 0.5f * x * (1.0f + erff(x * 0.70710678118654752f));
}
__device__ __forceinline__ float siluf(float x) {
    return x / (1.0f + __expf(-x));
}
__device__ __forceinline__ float softplusf(float x) {
    return (x > 20.0f) ? x : log1pf(expf(x));
}
__device__ __forceinline__ float b2f(bf16_t v) { return __bfloat162float(v); }

// butterfly sum over 16-lane groups
__device__ __forceinline__ float red16(float p) {
    p += __int_as_float(__builtin_amdgcn_mov_dpp(__float_as_int(p), 0xB1, 0xF, 0xF, true));   // xor1
    p += __int_as_float(__builtin_amdgcn_mov_dpp(__float_as_int(p), 0x4E, 0xF, 0xF, true));   // xor2
    p += __int_as_float(__builtin_amdgcn_ds_swizzle(__float_as_int(p), 0x101F));              // xor4
    p += __int_as_float(__builtin_amdgcn_mov_dpp(__float_as_int(p), 0x128, 0xF, 0xF, true));  // ror8 == xor8
    return p;
}

// dual 256-thread block sum; sm must have >= 8 floats
__device__ __forceinline__ float2 block_sum256_2(float a, float b, float* sm) {
    int tid = threadIdx.x;
    #pragma unroll
    for (int off = 32; off > 0; off >>= 1) {
        a += __shfl_down(a, off, 64);
        b += __shfl_down(b, off, 64);
    }
    __syncthreads();
    if ((tid & 63) == 0) { sm[tid >> 6] = a; sm[4 + (tid >> 6)] = b; }
    __syncthreads();
    float2 r;
    r.x = sm[0] + sm[1] + sm[2] + sm[3];
    r.y = sm[4] + sm[5] + sm[6] + sm[7];
    return r;
}

// ---------------- one-shot batched weight transpose + bf16 convert
// z = which*NL + layer; src fp32 [R][C] -> dst bf16 [C][R]
__global__ void k_transpose_all(const float* __restrict__ in_w,
                                const float* __restrict__ xp_w,
                                const float* __restrict__ out_w,
                                bf16_t* __restrict__ in_wT,
                                bf16_t* __restrict__ xp_wT,
                                bf16_t* __restrict__ out_wT) {
    __shared__ float t[32][33];
    int z = blockIdx.z;
    int which = z >> 2, layer = z & 3;
    const float* src; bf16_t* dst; int R, C;
    if (which == 0)      { R = DM_; C = 2 * ED_; src = in_w;  dst = in_wT;  }
    else if (which == 1) { R = ED_; C = 48;      src = xp_w;  dst = xp_wT;  }
    else                 { R = ED_; C = DM_;     src = out_w; dst = out_wT; }
    src += (size_t)layer * R * C;
    dst += (size_t)layer * R * C;
    int c0 = blockIdx.x * 32, r0 = blockIdx.y * 32;
    if (c0 >= C || r0 >= R) return;
    int tx = threadIdx.x & 31, ty = threadIdx.x >> 5;   // 32 x 8
    #pragma unroll
    for (int i = 0; i < 32; i += 8) {
        int r = r0 + ty + i, c = c0 + tx;
        t[ty + i][tx] = (r < R && c < C) ? src[(size_t)r * C + c] : 0.f;
    }
    __syncthreads();
    #pragma unroll
    for (int i = 0; i < 32; i += 8) {
        int c = c0 + ty + i, r = r0 + tx;
        if (c < C && r < R) dst[(size_t)c * R + r] = __float2bfloat16(t[tx][ty + i]);
    }
}

// ---------------- embed
__global__ void k_embed(const int* __restrict__ tokens,
                        const float* __restrict__ tok_embed,
                        const float* __restrict__ pos_embed,
                        float* __restrict__ x) {
    int row = blockIdx.x;
    int d = threadIdx.x;
    int b = row / L_, l = row % L_;
    float v = pos_embed[l * DM_ + d];
    if (l > 0) {
        int tok = tokens[b * L_ + l - 1];
        v += tok_embed[tok * DM_ + d];
    }
    x[row * DM_ + d] = v;
}

// ---------------- conditioning + all-layer adaLN params in one launch
// grid (B_, NL_), 512 threads
__global__ void k_prep(const float* __restrict__ T,
                       const float* __restrict__ tw1, const float* __restrict__ tb1,
                       const float* __restrict__ tw2, const float* __restrict__ tb2,
                       const float* __restrict__ apw, const float* __restrict__ apb,
                       float* __restrict__ ss) {
    __shared__ float h[CD_], cnd[CD_];
    int b = blockIdx.x, layer = blockIdx.y;
    int j = threadIdx.x;
    if (j < CD_) h[j] = geluf(T[b] * tw1[j] + tb1[j]);
    __syncthreads();
    if (j < CD_) {
        float acc = tb2[j];
        #pragma unroll
        for (int c = 0; c < CD_; c++) acc += h[c] * tw2[c * CD_ + j];
        cnd[j] = acc;
    }
    __syncthreads();
    const float* w = apw + (size_t)layer * CD_ * 2 * DM_;
    float acc = apb[layer * 2 * DM_ + j];
    #pragma unroll
    for (int c = 0; c < CD_; c++) acc += cnd[c] * w[c * 2 * DM_ + j];
    ss[((size_t)layer * B_ + b) * 2 * DM_ + j] = acc;
}

// ---------------- LN + adaLN modulation -> bf16 xn (single-pass sum/sumsq)
__global__ void k_lnmod(const float* __restrict__ x,
                        const float* __restrict__ ag, const float* __restrict__ ab,
                        const float* __restrict__ ss,
                        bf16_t* __restrict__ xn, int layer) {
    __shared__ float sm[8];
    int row = blockIdx.x;
    int d = threadIdx.x;
    int b = row / L_;
    float v = x[row * DM_ + d];
    float2 s = block_sum256_2(v, v * v, sm);
    float mean = s.x * (1.0f / DM_);
    float var = s.y * (1.0f / DM_) - mean * mean;
    float rstd = rsqrtf(var + 1e-5f);
    float ln = (v - mean) * rstd * ag[layer * DM_ + d] + ab[layer * DM_ + d];
    const float* ssl = ss + ((size_t)layer * B_ + b) * 2 * DM_;
    xn[row * DM_ + d] = __float2bfloat16((1.0f + ssl[d]) * ln + ssl[DM_ + d]);
}

// ---------------- MFMA bf16 GEMM: C[M,N] (+)= A[M,K] @ Bt[N,K]^T
template<int BM, int BN, bool OUT_BF16, bool ACCUM>
__global__ __launch_bounds__(256) void k_mfma_gemm(
        const bf16_t* __restrict__ A, const bf16_t* __restrict__ Bt,
        float* __restrict__ Cf, bf16_t* __restrict__ Cb,
        int M, int N, int K) {
    constexpr int TM = BM / 32, TN = BN / 32;
    constexpr int NA = BM * 4 / 256;
    constexpr int NB = BN * 4 / 256;
    __shared__ __align__(16) unsigned short sA[BM * 40];
    __shared__ __align__(16) unsigned short sB[BN * 40];

    const int tid = threadIdx.x;
    const int wave = tid >> 6, lane = tid & 63;
    const int lrow = lane & 15, lq = lane >> 4;
    const int row0 = blockIdx.y * BM, col0 = blockIdx.x * BN;
    const int wm0 = (wave >> 1) * (BM / 2);
    const int wn0 = (wave & 1) * (BN / 2);

    floatx4 acc[TM][TN];
    #pragma unroll
    for (int i = 0; i < TM; i++)
        #pragma unroll
        for (int j = 0; j < TN; j++) acc[i][j] = (floatx4)0.0f;

    short8 ra[NA], rb[NB];
    const int NKB = K / 32;

    #pragma unroll
    for (int i = 0; i < NA; i++) {
        int vid = tid + i * 256; int m = vid >> 2, ko = (vid & 3) * 8;
        ra[i] = *(const short8*)(A + (size_t)(row0 + m) * K + ko);
    }
    #pragma unroll
    for (int i = 0; i < NB; i++) {
        int vid = tid + i * 256; int n = vid >> 2, ko = (vid & 3) * 8;
        int gn = col0 + n;
        rb[i] = (gn < N) ? *(const short8*)(Bt + (size_t)gn * K + ko) : (short8)0;
    }

    for (int kb = 0; kb < NKB; kb++) {
        __syncthreads();
        #pragma unroll
        for (int i = 0; i < NA; i++) {
            int vid = tid + i * 256; int m = vid >> 2, ko = (vid & 3) * 8;
            *(short8*)&sA[m * 40 + ko] = ra[i];
        }
        #pragma unroll
        for (int i = 0; i < NB; i++) {
            int vid = tid + i * 256; int n = vid >> 2, ko = (vid & 3) * 8;
            *(short8*)&sB[n * 40 + ko] = rb[i];
        }
        __syncthreads();
        if (kb + 1 < NKB) {
            int k0 = (kb + 1) * 32;
            #pragma unroll
            for (int i = 0; i < NA; i++) {
                int vid = tid + i * 256; int m = vid >> 2, ko = (vid & 3) * 8;
                ra[i] = *(const short8*)(A + (size_t)(row0 + m) * K + k0 + ko);
            }
            #pragma unroll
            for (int i = 0; i < NB; i++) {
                int vid = tid + i * 256; int n = vid >> 2, ko = (vid & 3) * 8;
                int gn = col0 + n;
                rb[i] = (gn < N) ? *(const short8*)(Bt + (size_t)gn * K + k0 + ko) : (short8)0;
            }
        }
        short8 af[TM], bfr[TN];
        #pragma unroll
        for (int i = 0; i < TM; i++)
            af[i] = *(const short8*)&sA[(wm0 + i * 16 + lrow) * 40 + lq * 8];
        #pragma unroll
        for (int j = 0; j < TN; j++)
            bfr[j] = *(const short8*)&sB[(wn0 + j * 16 + lrow) * 40 + lq * 8];
        #pragma unroll
        for (int i = 0; i < TM; i++)
            #pragma unroll
            for (int j = 0; j < TN; j++)
                acc[i][j] = __builtin_amdgcn_mfma_f32_16x16x32_bf16(af[i], bfr[j], acc[i][j], 0, 0, 0);
    }

    #pragma unroll
    for (int i = 0; i < TM; i++) {
        int gr0 = row0 + wm0 + i * 16 + lq * 4;
        #pragma unroll
        for (int j = 0; j < TN; j++) {
            int gc = col0 + wn0 + j * 16 + lrow;
            if (gc < N) {
                #pragma unroll
                for (int r = 0; r < 4; r++) {
                    size_t idx = (size_t)(gr0 + r) * N + gc;
                    if (OUT_BF16)      Cb[idx] = __float2bfloat16(acc[i][j][r]);
                    else if (ACCUM)    Cf[idx] += acc[i][j][r];
                    else               Cf[idx] = acc[i][j][r];
                }
            }
        }
    }
}

// ---------------- causal depthwise conv (DC=4) + SiLU: bf16 in/out, 2 e per thread
__global__ void k_conv(const bf16_t* __restrict__ xz,
                       const float* __restrict__ conv_w, const float* __restrict__ conv_b,
                       bf16_t* __restrict__ xs, int layer) {
    int t = blockIdx.x * blockDim.x + threadIdx.x;   // ROWS * ED/2
    int ep = t % (ED_ / 2);
    int row = t / (ED_ / 2);
    int e = ep * 2;
    int b = row / L_, l = row % L_;
    float4 w0 = *(const float4*)(conv_w + ((size_t)layer * ED_ + e) * DC_);
    float4 w1 = *(const float4*)(conv_w + ((size_t)layer * ED_ + e + 1) * DC_);
    float acc0 = conv_b[layer * ED_ + e];
    float acc1 = conv_b[layer * ED_ + e + 1];
    const float wa0[4] = {w0.x, w0.y, w0.z, w0.w};
    const float wa1[4] = {w1.x, w1.y, w1.z, w1.w};
    #pragma unroll
    for (int k = 0; k < DC_; k++) {
        int ll = l - (DC_ - 1) + k;
        if (ll >= 0) {
            __hip_bfloat162 v = *(const __hip_bfloat162*)(xz + ((size_t)(b * L_ + ll)) * (2 * ED_) + e);
            acc0 += b2f(v.x) * wa0[k];
            acc1 += b2f(v.y) * wa1[k];
        }
    }
    __hip_bfloat162 o;
    o.x = __float2bfloat16(siluf(acc0));
    o.y = __float2bfloat16(siluf(acc1));
    *(__hip_bfloat162*)(xs + (size_t)row * ED_ + e) = o;
}

// ---------------- dlt = softplus(xd[:,:16] @ dt_w + dt_b) -> bf16, 2 e per thread
__global__ void k_dlt(const float* __restrict__ xd,
                      const float* __restrict__ dt_w, const float* __restrict__ dt_b,
                      bf16_t* __restrict__ dlt, int layer) {
    int t = blockIdx.x * blockDim.x + threadIdx.x;   // ROWS * ED/2
    int ep = t % (ED_ / 2);
    int row = t / (ED_ / 2);
    int e = ep * 2;
    float acc0 = dt_b[layer * ED_ + e];
    float acc1 = dt_b[layer * ED_ + e + 1];
    const float* w = dt_w + (size_t)layer * RK_ * ED_;
    const float* xr = xd + (size_t)row * (RK_ + 2 * NS_);
    #pragma unroll
    for (int r = 0; r < RK_; r++) {
        float xv = xr[r];
        float2 wv = *(const float2*)(w + r * ED_ + e);
        acc0 += xv * wv.x;
        acc1 += xv * wv.y;
    }
    __hip_bfloat162 o;
    o.x = __float2bfloat16(softplusf(acc0));
    o.y = __float2bfloat16(softplusf(acc1));
    *(__hip_bfloat162*)(dlt + (size_t)row * ED_ + e) = o;
}

// ======== chunked selective scan: SEG_=16 segments of 64 steps ====
// state buffers indexed [(b*32+etile)*SEG + seg]*256 + tid, tid = et*16+n
// grid decode: seg = bi & 15, etile = (bi>>4) & 31, b = bi >> 9

// phase 1: local recurrence from h=0; emit P = prod(a), h_end
__global__ __launch_bounds__(256) void k_scan1(
        const bf16_t* __restrict__ dlt, const bf16_t* __restrict__ xs,
        const float* __restrict__ xd,    // Bm at +16 (row stride 48)
        const float* __restrict__ A_log,
        float* __restrict__ aprod, float* __restrict__ hend, int layer) {
    __shared__ float s_dlt[16 * PAD_];
    __shared__ float s_xs [16 * PAD_];
    __shared__ float s_B  [16 * PAD_];

    const int tid = threadIdx.x;
    const int n  = tid & 15;
    const int et = tid >> 4;
    const int bi = blockIdx.x;
    const int seg = bi & (SEG_ - 1);
    const int etile = (bi >> 4) & 31;
    const int b = bi >> 9;
    const int e0 = etile << 4;
    const int e  = e0 + et;

    const float A = -__expf(A_log[((size_t)layer * ED_ + e) * NS_ + n]);

    const int le = tid & 15;
    const int lj = tid >> 4;
    const int rowbase = b * L_ + seg * SLEN_;

    #pragma unroll
    for (int j = 0; j < 4; j++) {
        int ll = lj + 16 * j;
        size_t row = rowbase + ll;
        s_dlt[le * PAD_ + ll] = b2f(dlt[row * ED_ + e0 + le]);
        s_xs [le * PAD_ + ll] = b2f(xs [row * ED_ + e0 + le]);
        s_B  [le * PAD_ + ll] = xd [row * 48 + 16 + le];
    }
    __syncthreads();

    float h = 0.0f, P = 1.0f;
    #pragma unroll
    for (int s = 0; s < SLEN_ / 8; s++) {
        float4 d0 = *(const float4*)&s_dlt[et * PAD_ + s * 8];
        float4 d1 = *(const float4*)&s_dlt[et * PAD_ + s * 8 + 4];
        float4 x0 = *(const float4*)&s_xs [et * PAD_ + s * 8];
        float4 x1 = *(const float4*)&s_xs [et * PAD_ + s * 8 + 4];
        float4 B0 = *(const float4*)&s_B  [n  * PAD_ + s * 8];
        float4 B1 = *(const float4*)&s_B  [n  * PAD_ + s * 8 + 4];
        float dv[8] = {d0.x, d0.y, d0.z, d0.w, d1.x, d1.y, d1.z, d1.w};
        float xv[8] = {x0.x, x0.y, x0.z, x0.w, x1.x, x1.y, x1.z, x1.w};
        float Bv[8] = {B0.x, B0.y, B0.z, B0.w, B1.x, B1.y, B1.z, B1.w};
        #pragma unroll
        for (int jj = 0; jj < 8; jj++) {
            float a = __expf(dv[jj] * A);
            h = fmaf(a, h, (dv[jj] * xv[jj]) * Bv[jj]);
            P *= a;
        }
    }
    size_t idx = (((size_t)(b * 32 + etile) * SEG_ + seg) << 8) + tid;
    aprod[idx] = P;
    hend[idx]  = h;
}

// phase 3: full scan seeded with inline prefix of (aprod,hend); reduction + D + gate.
// y aliases dlt: block reads its segment's dlt rows (staging) before writing y rows.
__global__ __launch_bounds__(256) void k_scan3(
        const bf16_t* dlt, const bf16_t* __restrict__ xs,
        const float* __restrict__ xd,    // Bm at +16, Cm at +32 (row stride 48)
        const bf16_t* __restrict__ xz,   // z at +ED
        const float* __restrict__ A_log, const float* __restrict__ Dp,
        const float* __restrict__ aprod, const float* __restrict__ hend,
        bf16_t* y, int layer) {
    __shared__ float s_dlt[16 * PAD_];
    __shared__ float s_xs [16 * PAD_];
    __shared__ float s_B  [16 * PAD_];
    __shared__ float s_C  [16 * PAD_];
    __shared__ float s_z  [16 * PAD_];
    __shared__ float s_y  [16 * PAD_];

    const int tid = threadIdx.x;
    const int n  = tid & 15;
    const int et = tid >> 4;
    const int bi = blockIdx.x;
    const int seg = bi & (SEG_ - 1);
    const int etile = (bi >> 4) & 31;
    const int b = bi >> 9;
    const int e0 = etile << 4;
    const int e  = e0 + et;

    const float A = -__expf(A_log[((size_t)layer * ED_ + e) * NS_ + n]);
    const float D = Dp[layer * ED_ + e];

    // inline cross-segment prefix (block-uniform trip count)
    const size_t base = ((size_t)(b * 32 + etile) * SEG_) << 8;
    float h = 0.0f;
    for (int s = 0; s < seg; s++) {
        size_t idx = base + ((size_t)s << 8) + tid;
        h = aprod[idx] * h + hend[idx];
    }

    const int le = tid & 15;
    const int lj = tid >> 4;
    const int rowbase = b * L_ + seg * SLEN_;

    #pragma unroll
    for (int j = 0; j < 4; j++) {
        int ll = lj + 16 * j;
        size_t row = rowbase + ll;
        s_dlt[le * PAD_ + ll] = b2f(dlt[row * ED_ + e0 + le]);
        s_xs [le * PAD_ + ll] = b2f(xs [row * ED_ + e0 + le]);
        s_B  [le * PAD_ + ll] = xd [row * 48 + 16 + le];
        s_C  [le * PAD_ + ll] = xd [row * 48 + 32 + le];
        s_z  [le * PAD_ + ll] = b2f(xz [row * (2 * ED_) + ED_ + e0 + le]);
    }
    __syncthreads();

    #pragma unroll
    for (int s = 0; s < SLEN_ / 8; s++) {
        float4 d0 = *(const float4*)&s_dlt[et * PAD_ + s * 8];
        float4 d1 = *(const float4*)&s_dlt[et * PAD_ + s * 8 + 4];
        float4 x0 = *(const float4*)&s_xs [et * PAD_ + s * 8];
        float4 x1 = *(const float4*)&s_xs [et * PAD_ + s * 8 + 4];
        float4 B0 = *(const float4*)&s_B  [n  * PAD_ + s * 8];
        float4 B1 = *(const float4*)&s_B  [n  * PAD_ + s * 8 + 4];
        float4 C0 = *(const float4*)&s_C  [n  * PAD_ + s * 8];
        float4 C1 = *(const float4*)&s_C  [n  * PAD_ + s * 8 + 4];
        float dv[8] = {d0.x, d0.y, d0.z, d0.w, d1.x, d1.y, d1.z, d1.w};
        float xv[8] = {x0.x, x0.y, x0.z, x0.w, x1.x, x1.y, x1.z, x1.w};
        float Bv[8] = {B0.x, B0.y, B0.z, B0.w, B1.x, B1.y, B1.z, B1.w};
        float Cv[8] = {C0.x, C0.y, C0.z, C0.w, C1.x, C1.y, C1.z, C1.w};
        #pragma unroll
        for (int jj = 0; jj < 8; jj++) {
            float a = __expf(dv[jj] * A);
            h = fmaf(a, h, (dv[jj] * xv[jj]) * Bv[jj]);
            float p = red16(h * Cv[jj]);
            if (n == 0) s_y[et * PAD_ + s * 8 + jj] = p + D * xv[jj];
        }
    }
    __syncthreads();
    #pragma unroll
    for (int j = 0; j < 4; j++) {
        int ll = lj + 16 * j;
        size_t row = rowbase + ll;
        y[row * ED_ + e0 + le] =
            __float2bfloat16(s_y[le * PAD_ + ll] * siluf(s_z[le * PAD_ + ll]));
    }
}

// ---------------- final LN + head (fused dual reductions)
__global__ void k_final(const float* __restrict__ x,
                        const float* __restrict__ fg, const float* __restrict__ fb,
                        const float* __restrict__ hw, const float* __restrict__ hb,
                        float* __restrict__ out) {
    __shared__ float sm[8];
    int row = blockIdx.x;
    int d = threadIdx.x;
    float v = x[row * DM_ + d];
    float2 s = block_sum256_2(v, v * v, sm);
    float mean = s.x * (1.0f / DM_);
    float var = s.y * (1.0f / DM_) - mean * mean;
    float rstd = rsqrtf(var + 1e-5f);
    float xf = (v - mean) * rstd * fg[d] + fb[d];
    float2 hsum = block_sum256_2(xf * hw[d * Q_ + 0], xf * hw[d * Q_ + 1], sm);
    if (d < Q_) {
        float sv = (d == 0) ? hsum.x : hsum.y;
        out[row * Q_ + d] = sv + hb[d];
    }
}

extern "C" void kernel_launch(void* const* d_in, const int* in_sizes, int n_in,
                              void* d_out, int out_size, void* d_ws, size_t ws_size,
                              hipStream_t stream) {
    const int*   tokens    = (const int*)d_in[0];
    const float* T         = (const float*)d_in[1];
    const float* tok_embed = (const float*)d_in[2];
    const float* pos_embed = (const float*)d_in[3];
    const float* tw1       = (const float*)d_in[4];
    const float* tb1       = (const float*)d_in[5];
    const float* tw2       = (const float*)d_in[6];
    const float* tb2       = (const float*)d_in[7];
    const float* ag        = (const float*)d_in[8];
    const float* ab        = (const float*)d_in[9];
    const float* apw       = (const float*)d_in[10];
    const float* apb       = (const float*)d_in[11];
    const float* in_w      = (const float*)d_in[12];
    const float* conv_w    = (const float*)d_in[13];
    const float* conv_b    = (const float*)d_in[14];
    const float* xp_w      = (const float*)d_in[15];
    const float* dt_w      = (const float*)d_in[16];
    const float* dt_b      = (const float*)d_in[17];
    const float* A_log     = (const float*)d_in[18];
    const float* Dp        = (const float*)d_in[19];
    const float* out_w     = (const float*)d_in[20];
    const float* fg        = (const float*)d_in[21];
    const float* fb        = (const float*)d_in[22];
    const float* hw        = (const float*)d_in[23];
    const float* hb        = (const float*)d_in[24];
    float* out = (float*)d_out;

    const int ROWS = B_ * L_;   // 8192

    char* p = (char*)d_ws;
    float*  x     = (float*)p;   p += (size_t)ROWS * DM_ * 4;
    bf16_t* xn    = (bf16_t*)p;  p += (size_t)ROWS * DM_ * 2;
    bf16_t* xz    = (bf16_t*)p;  p += (size_t)ROWS * 2 * ED_ * 2;
    bf16_t* xs    = (bf16_t*)p;  p += (size_t)ROWS * ED_ * 2;
    float*  xd    = (float*)p;   p += (size_t)ROWS * 48 * 4;
    bf16_t* dlt   = (bf16_t*)p;  p += (size_t)ROWS * ED_ * 2;
    bf16_t* y     = dlt;         // alias, safe per k_scan3 structure
    float*  ss    = (float*)p;   p += (size_t)NL_ * B_ * 2 * DM_ * 4;
    float*  aprod = (float*)p;   p += (size_t)B_ * ED_ * NS_ * SEG_ * 4;  // 4 MB
    float*  hend  = (float*)p;   p += (size_t)B_ * ED_ * NS_ * SEG_ * 4;  // 4 MB
    bf16_t* in_wT = (bf16_t*)p;  p += (size_t)NL_ * 2 * ED_ * DM_ * 2;
    bf16_t* xp_wT = (bf16_t*)p;  p += (size_t)NL_ * 48 * ED_ * 2;
    bf16_t* out_wT= (bf16_t*)p;  p += (size_t)NL_ * DM_ * ED_ * 2;

    // one-time weight transposes (bf16, [N][K]) — single launch
    k_transpose_all<<<dim3(32, 16, 12), 256, 0, stream>>>(
        in_w, xp_w, out_w, in_wT, xp_wT, out_wT);
    // cond + all-layer ss — single launch
    k_prep<<<dim3(B_, NL_), 2 * DM_, 0, stream>>>(T, tw1, tb1, tw2, tb2, apw, apb, ss);

    k_embed<<<ROWS, DM_, 0, stream>>>(tokens, tok_embed, pos_embed, x);

    for (int i = 0; i < NL_; i++) {
        k_lnmod<<<ROWS, DM_, 0, stream>>>(x, ag, ab, ss, xn, i);
        // xz = xn @ in_w[i]   (8192 x 256 x 1024), bf16 out
        k_mfma_gemm<128, 128, true, false><<<dim3(2 * ED_ / 128, ROWS / 128), 256, 0, stream>>>(
            xn, in_wT + (size_t)i * 2 * ED_ * DM_, nullptr, xz, ROWS, 2 * ED_, DM_);
        k_conv<<<ROWS * (ED_ / 2) / 256, 256, 0, stream>>>(xz, conv_w, conv_b, xs, i);
        // xd = xs @ xp_w[i]   (8192 x 512 x 48), fp32 out
        k_mfma_gemm<64, 64, false, false><<<dim3(1, ROWS / 64), 256, 0, stream>>>(
            xs, xp_wT + (size_t)i * 48 * ED_, xd, nullptr, ROWS, 48, ED_);
        k_dlt<<<ROWS * (ED_ / 2) / 256, 256, 0, stream>>>(xd, dt_w, dt_b, dlt, i);
        // chunked scan (SEG_=16, 64-step segments)
        k_scan1<<<B_ * 32 * SEG_, 256, 0, stream>>>(dlt, xs, xd, A_log, aprod, hend, i);
        k_scan3<<<B_ * 32 * SEG_, 256, 0, stream>>>(dlt, xs, xd, xz, A_log, Dp, aprod, hend, y, i);
        // x += y @ out_w[i]   (8192 x 512 x 256), fp32 accumulate
        k_mfma_gemm<128, 64, false, true><<<dim3(DM_ / 64, ROWS / 128), 256, 0, stream>>>(
            y, out_wT + (size_t)i * DM_ * ED_, x, nullptr, ROWS, DM_, ED_);
    }

    k_final<<<ROWS, DM_, 0, stream>>>(x, fg, fb, hw, hb, out);
}

// Round 7
// 688.077 us; speedup vs baseline: 6.9191x; 1.0140x over previous
//
#include <hip/hip_runtime.h>
#include <hip/hip_bf16.h>
#include <math.h>

#define B_   8
#define L_   1024
#define DM_  256
#define NL_  4
#define ED_  512
#define NS_  16
#define DC_  4
#define RK_  16
#define CD_  64
#define Q_   2

#define SEG_  16    // segments along L for chunked scan
#define SLEN_ 64    // L_/SEG_

typedef __hip_bfloat16 bf16_t;
typedef __attribute__((ext_vector_type(8))) short short8;
typedef __attribute__((ext_vector_type(4))) float floatx4;

__device__ __forceinline__ float geluf(float x) {
    return 0.5f * x * (1.0f + erff(x * 0.70710678118654752f));
}
__device__ __forceinline__ float siluf(float x) {
    return x / (1.0f + __expf(-x));
}
__device__ __forceinline__ float softplusf(float x) {
    return (x > 20.0f) ? x : log1pf(expf(x));
}
__device__ __forceinline__ float b2f(bf16_t v) { return __bfloat162float(v); }

// dual 256-thread block sum; sm must have >= 8 floats
__device__ __forceinline__ float2 block_sum256_2(float a, float b, float* sm) {
    int tid = threadIdx.x;
    #pragma unroll
    for (int off = 32; off > 0; off >>= 1) {
        a += __shfl_down(a, off, 64);
        b += __shfl_down(b, off, 64);
    }
    __syncthreads();
    if ((tid & 63) == 0) { sm[tid >> 6] = a; sm[4 + (tid >> 6)] = b; }
    __syncthreads();
    float2 r;
    r.x = sm[0] + sm[1] + sm[2] + sm[3];
    r.y = sm[4] + sm[5] + sm[6] + sm[7];
    return r;
}

// ---------------- one-shot batched weight transpose + bf16 convert
__global__ void k_transpose_all(const float* __restrict__ in_w,
                                const float* __restrict__ xp_w,
                                const float* __restrict__ out_w,
                                bf16_t* __restrict__ in_wT,
                                bf16_t* __restrict__ xp_wT,
                                bf16_t* __restrict__ out_wT) {
    __shared__ float t[32][33];
    int z = blockIdx.z;
    int which = z >> 2, layer = z & 3;
    const float* src; bf16_t* dst; int R, C;
    if (which == 0)      { R = DM_; C = 2 * ED_; src = in_w;  dst = in_wT;  }
    else if (which == 1) { R = ED_; C = 48;      src = xp_w;  dst = xp_wT;  }
    else                 { R = ED_; C = DM_;     src = out_w; dst = out_wT; }
    src += (size_t)layer * R * C;
    dst += (size_t)layer * R * C;
    int c0 = blockIdx.x * 32, r0 = blockIdx.y * 32;
    if (c0 >= C || r0 >= R) return;
    int tx = threadIdx.x & 31, ty = threadIdx.x >> 5;   // 32 x 8
    #pragma unroll
    for (int i = 0; i < 32; i += 8) {
        int r = r0 + ty + i, c = c0 + tx;
        t[ty + i][tx] = (r < R && c < C) ? src[(size_t)r * C + c] : 0.f;
    }
    __syncthreads();
    #pragma unroll
    for (int i = 0; i < 32; i += 8) {
        int c = c0 + ty + i, r = r0 + tx;
        if (c < C && r < R) dst[(size_t)c * R + r] = __float2bfloat16(t[tx][ty + i]);
    }
}

// ---------------- embed
__global__ void k_embed(const int* __restrict__ tokens,
                        const float* __restrict__ tok_embed,
                        const float* __restrict__ pos_embed,
                        float* __restrict__ x) {
    int row = blockIdx.x;
    int d = threadIdx.x;
    int b = row / L_, l = row % L_;
    float v = pos_embed[l * DM_ + d];
    if (l > 0) {
        int tok = tokens[b * L_ + l - 1];
        v += tok_embed[tok * DM_ + d];
    }
    x[row * DM_ + d] = v;
}

// ---------------- conditioning + all-layer adaLN params in one launch
__global__ void k_prep(const float* __restrict__ T,
                       const float* __restrict__ tw1, const float* __restrict__ tb1,
                       const float* __restrict__ tw2, const float* __restrict__ tb2,
                       const float* __restrict__ apw, const float* __restrict__ apb,
                       float* __restrict__ ss) {
    __shared__ float h[CD_], cnd[CD_];
    int b = blockIdx.x, layer = blockIdx.y;
    int j = threadIdx.x;
    if (j < CD_) h[j] = geluf(T[b] * tw1[j] + tb1[j]);
    __syncthreads();
    if (j < CD_) {
        float acc = tb2[j];
        #pragma unroll
        for (int c = 0; c < CD_; c++) acc += h[c] * tw2[c * CD_ + j];
        cnd[j] = acc;
    }
    __syncthreads();
    const float* w = apw + (size_t)layer * CD_ * 2 * DM_;
    float acc = apb[layer * 2 * DM_ + j];
    #pragma unroll
    for (int c = 0; c < CD_; c++) acc += cnd[c] * w[c * 2 * DM_ + j];
    ss[((size_t)layer * B_ + b) * 2 * DM_ + j] = acc;
}

// ---------------- LN + adaLN modulation -> bf16 xn
__global__ void k_lnmod(const float* __restrict__ x,
                        const float* __restrict__ ag, const float* __restrict__ ab,
                        const float* __restrict__ ss,
                        bf16_t* __restrict__ xn, int layer) {
    __shared__ float sm[8];
    int row = blockIdx.x;
    int d = threadIdx.x;
    int b = row / L_;
    float v = x[row * DM_ + d];
    float2 s = block_sum256_2(v, v * v, sm);
    float mean = s.x * (1.0f / DM_);
    float var = s.y * (1.0f / DM_) - mean * mean;
    float rstd = rsqrtf(var + 1e-5f);
    float ln = (v - mean) * rstd * ag[layer * DM_ + d] + ab[layer * DM_ + d];
    const float* ssl = ss + ((size_t)layer * B_ + b) * 2 * DM_;
    xn[row * DM_ + d] = __float2bfloat16((1.0f + ssl[d]) * ln + ssl[DM_ + d]);
}

// ---------------- MFMA bf16 GEMM: C[M,N] (+)= A[M,K] @ Bt[N,K]^T
template<int BM, int BN, bool OUT_BF16, bool ACCUM>
__global__ __launch_bounds__(256) void k_mfma_gemm(
        const bf16_t* __restrict__ A, const bf16_t* __restrict__ Bt,
        float* __restrict__ Cf, bf16_t* __restrict__ Cb,
        int M, int N, int K) {
    constexpr int TM = BM / 32, TN = BN / 32;
    constexpr int NA = BM * 4 / 256;
    constexpr int NB = BN * 4 / 256;
    __shared__ __align__(16) unsigned short sA[BM * 40];
    __shared__ __align__(16) unsigned short sB[BN * 40];

    const int tid = threadIdx.x;
    const int wave = tid >> 6, lane = tid & 63;
    const int lrow = lane & 15, lq = lane >> 4;
    const int row0 = blockIdx.y * BM, col0 = blockIdx.x * BN;
    const int wm0 = (wave >> 1) * (BM / 2);
    const int wn0 = (wave & 1) * (BN / 2);

    floatx4 acc[TM][TN];
    #pragma unroll
    for (int i = 0; i < TM; i++)
        #pragma unroll
        for (int j = 0; j < TN; j++) acc[i][j] = (floatx4)0.0f;

    short8 ra[NA], rb[NB];
    const int NKB = K / 32;

    #pragma unroll
    for (int i = 0; i < NA; i++) {
        int vid = tid + i * 256; int m = vid >> 2, ko = (vid & 3) * 8;
        ra[i] = *(const short8*)(A + (size_t)(row0 + m) * K + ko);
    }
    #pragma unroll
    for (int i = 0; i < NB; i++) {
        int vid = tid + i * 256; int n = vid >> 2, ko = (vid & 3) * 8;
        int gn = col0 + n;
        rb[i] = (gn < N) ? *(const short8*)(Bt + (size_t)gn * K + ko) : (short8)0;
    }

    for (int kb = 0; kb < NKB; kb++) {
        __syncthreads();
        #pragma unroll
        for (int i = 0; i < NA; i++) {
            int vid = tid + i * 256; int m = vid >> 2, ko = (vid & 3) * 8;
            *(short8*)&sA[m * 40 + ko] = ra[i];
        }
        #pragma unroll
        for (int i = 0; i < NB; i++) {
            int vid = tid + i * 256; int n = vid >> 2, ko = (vid & 3) * 8;
            *(short8*)&sB[n * 40 + ko] = rb[i];
        }
        __syncthreads();
        if (kb + 1 < NKB) {
            int k0 = (kb + 1) * 32;
            #pragma unroll
            for (int i = 0; i < NA; i++) {
                int vid = tid + i * 256; int m = vid >> 2, ko = (vid & 3) * 8;
                ra[i] = *(const short8*)(A + (size_t)(row0 + m) * K + k0 + ko);
            }
            #pragma unroll
            for (int i = 0; i < NB; i++) {
                int vid = tid + i * 256; int n = vid >> 2, ko = (vid & 3) * 8;
                int gn = col0 + n;
                rb[i] = (gn < N) ? *(const short8*)(Bt + (size_t)gn * K + k0 + ko) : (short8)0;
            }
        }
        short8 af[TM], bfr[TN];
        #pragma unroll
        for (int i = 0; i < TM; i++)
            af[i] = *(const short8*)&sA[(wm0 + i * 16 + lrow) * 40 + lq * 8];
        #pragma unroll
        for (int j = 0; j < TN; j++)
            bfr[j] = *(const short8*)&sB[(wn0 + j * 16 + lrow) * 40 + lq * 8];
        #pragma unroll
        for (int i = 0; i < TM; i++)
            #pragma unroll
            for (int j = 0; j < TN; j++)
                acc[i][j] = __builtin_amdgcn_mfma_f32_16x16x32_bf16(af[i], bfr[j], acc[i][j], 0, 0, 0);
    }

    #pragma unroll
    for (int i = 0; i < TM; i++) {
        int gr0 = row0 + wm0 + i * 16 + lq * 4;
        #pragma unroll
        for (int j = 0; j < TN; j++) {
            int gc = col0 + wn0 + j * 16 + lrow;
            if (gc < N) {
                #pragma unroll
                for (int r = 0; r < 4; r++) {
                    size_t idx = (size_t)(gr0 + r) * N + gc;
                    if (OUT_BF16)      Cb[idx] = __float2bfloat16(acc[i][j][r]);
                    else if (ACCUM)    Cf[idx] += acc[i][j][r];
                    else               Cf[idx] = acc[i][j][r];
                }
            }
        }
    }
}

// ---------------- causal depthwise conv (DC=4) + SiLU: bf16 in/out, 2 e per thread
__global__ void k_conv(const bf16_t* __restrict__ xz,
                       const float* __restrict__ conv_w, const float* __restrict__ conv_b,
                       bf16_t* __restrict__ xs, int layer) {
    int t = blockIdx.x * blockDim.x + threadIdx.x;
    int ep = t % (ED_ / 2);
    int row = t / (ED_ / 2);
    int e = ep * 2;
    int b = row / L_, l = row % L_;
    float4 w0 = *(const float4*)(conv_w + ((size_t)layer * ED_ + e) * DC_);
    float4 w1 = *(const float4*)(conv_w + ((size_t)layer * ED_ + e + 1) * DC_);
    float acc0 = conv_b[layer * ED_ + e];
    float acc1 = conv_b[layer * ED_ + e + 1];
    const float wa0[4] = {w0.x, w0.y, w0.z, w0.w};
    const float wa1[4] = {w1.x, w1.y, w1.z, w1.w};
    #pragma unroll
    for (int k = 0; k < DC_; k++) {
        int ll = l - (DC_ - 1) + k;
        if (ll >= 0) {
            __hip_bfloat162 v = *(const __hip_bfloat162*)(xz + ((size_t)(b * L_ + ll)) * (2 * ED_) + e);
            acc0 += b2f(v.x) * wa0[k];
            acc1 += b2f(v.y) * wa1[k];
        }
    }
    __hip_bfloat162 o;
    o.x = __float2bfloat16(siluf(acc0));
    o.y = __float2bfloat16(siluf(acc1));
    *(__hip_bfloat162*)(xs + (size_t)row * ED_ + e) = o;
}

// ---------------- dlt = softplus(xd[:,:16] @ dt_w + dt_b) -> bf16, 2 e per thread
__global__ void k_dlt(const float* __restrict__ xd,
                      const float* __restrict__ dt_w, const float* __restrict__ dt_b,
                      bf16_t* __restrict__ dlt, int layer) {
    int t = blockIdx.x * blockDim.x + threadIdx.x;
    int ep = t % (ED_ / 2);
    int row = t / (ED_ / 2);
    int e = ep * 2;
    float acc0 = dt_b[layer * ED_ + e];
    float acc1 = dt_b[layer * ED_ + e + 1];
    const float* w = dt_w + (size_t)layer * RK_ * ED_;
    const float* xr = xd + (size_t)row * (RK_ + 2 * NS_);
    #pragma unroll
    for (int r = 0; r < RK_; r++) {
        float xv = xr[r];
        float2 wv = *(const float2*)(w + r * ED_ + e);
        acc0 += xv * wv.x;
        acc1 += xv * wv.y;
    }
    __hip_bfloat162 o;
    o.x = __float2bfloat16(softplusf(acc0));
    o.y = __float2bfloat16(softplusf(acc1));
    *(__hip_bfloat162*)(dlt + (size_t)row * ED_ + e) = o;
}

// ======== chunked selective scan, thread = (b, e, seg), 16 n-states in registers ====
// grid: B_ * 2 * SEG_ = 256 blocks, 256 threads. decode: seg=bi&15, eh=(bi>>4)&1, b=bi>>5
// P/hend layout: [b][seg][n][e] -> coalesced store + stitch-load.

// phase 1: local recurrence from h=0; emits P=prod(a), hend, and
// ylocal = sum_n C*h_local + D*x  (fp32)
__global__ __launch_bounds__(256) void k_scan1(
        const bf16_t* __restrict__ dlt, const bf16_t* __restrict__ xs,
        const float* __restrict__ xd,    // B at +16, C at +32 (row stride 48)
        const float* __restrict__ A_log, const float* __restrict__ Dp,
        float* __restrict__ aprod, float* __restrict__ hend,
        float* __restrict__ ylocal, int layer) {
    __shared__ float s_BC[64][32];
    const int te = threadIdx.x;
    const int bi = blockIdx.x;
    const int seg = bi & (SEG_ - 1);
    const int eh  = (bi >> 4) & 1;
    const int b   = bi >> 5;
    const int e   = eh * 256 + te;
    const int rowbase = b * L_ + seg * SLEN_;

    // stage B|C rows: 64 rows x 32 floats
    {
        int flat = te * 8;
        int r = flat >> 5, c = flat & 31;
        const float* src = xd + (size_t)(rowbase + r) * 48 + 16 + c;
        *(float4*)&s_BC[r][c]     = *(const float4*)(src);
        *(float4*)&s_BC[r][c + 4] = *(const float4*)(src + 4);
    }

    float A[16];
    {
        const float* ap = A_log + ((size_t)layer * ED_ + e) * NS_;
        #pragma unroll
        for (int n = 0; n < 16; n++) A[n] = -__expf(ap[n]);
    }
    const float D = Dp[layer * ED_ + e];

    float h[16], P[16];
    #pragma unroll
    for (int n = 0; n < 16; n++) { h[n] = 0.f; P[n] = 1.f; }

    const bf16_t* dptr = dlt + (size_t)rowbase * ED_ + e;
    const bf16_t* xptr = xs  + (size_t)rowbase * ED_ + e;
    float*        yptr = ylocal + (size_t)rowbase * ED_ + e;

    bf16_t dvb[8], xvb[8];
    #pragma unroll
    for (int j = 0; j < 8; j++) {
        dvb[j] = dptr[(size_t)j * ED_];
        xvb[j] = xptr[(size_t)j * ED_];
    }
    __syncthreads();

    for (int sub = 0; sub < 8; sub++) {
        bf16_t dnx[8], xnx[8];
        if (sub < 7) {
            const bf16_t* d2 = dptr + (size_t)(sub + 1) * 8 * ED_;
            const bf16_t* x2 = xptr + (size_t)(sub + 1) * 8 * ED_;
            #pragma unroll
            for (int j = 0; j < 8; j++) {
                dnx[j] = d2[(size_t)j * ED_];
                xnx[j] = x2[(size_t)j * ED_];
            }
        }
        #pragma unroll
        for (int j = 0; j < 8; j++) {
            int l = sub * 8 + j;
            float dv = b2f(dvb[j]), xv = b2f(xvb[j]);
            float dx = dv * xv;
            float Bv[16], Cv[16];
            #pragma unroll
            for (int q = 0; q < 4; q++) {
                *(float4*)&Bv[q * 4] = *(const float4*)&s_BC[l][q * 4];
                *(float4*)&Cv[q * 4] = *(const float4*)&s_BC[l][16 + q * 4];
            }
            float y0 = D * xv, y1 = 0.f, y2 = 0.f, y3 = 0.f;
            #pragma unroll
            for (int n = 0; n < 16; n++) {
                float a = __expf(dv * A[n]);
                h[n] = fmaf(a, h[n], dx * Bv[n]);
                P[n] *= a;
                float t = Cv[n] * h[n];
                if ((n & 3) == 0) y0 += t;
                else if ((n & 3) == 1) y1 += t;
                else if ((n & 3) == 2) y2 += t;
                else y3 += t;
            }
            yptr[(size_t)l * ED_] = (y0 + y1) + (y2 + y3);
        }
        #pragma unroll
        for (int j = 0; j < 8; j++) { dvb[j] = dnx[j]; xvb[j] = xnx[j]; }
    }

    #pragma unroll
    for (int n = 0; n < 16; n++) {
        size_t idx = ((((size_t)b * SEG_ + seg) << 4) + n) * ED_ + e;
        aprod[idx] = P[n];
        hend[idx]  = h[n];
    }
}

// phase 3: inline prefix over (P,hend) -> seed; homogeneous correction hc,
// y = (ylocal + sum_n C*hc) * silu(z), bf16 out.
__global__ __launch_bounds__(256) void k_scan3(
        const bf16_t* __restrict__ dlt,
        const bf16_t* __restrict__ xz,   // z at +ED
        const float* __restrict__ xd,    // C at +32 (row stride 48)
        const float* __restrict__ A_log,
        const float* __restrict__ aprod, const float* __restrict__ hend,
        const float* __restrict__ ylocal,
        bf16_t* __restrict__ y, int layer) {
    __shared__ float s_C[64][16];
    const int te = threadIdx.x;
    const int bi = blockIdx.x;
    const int seg = bi & (SEG_ - 1);
    const int eh  = (bi >> 4) & 1;
    const int b   = bi >> 5;
    const int e   = eh * 256 + te;
    const int rowbase = b * L_ + seg * SLEN_;

    // stage C rows: 64 x 16 floats
    {
        int flat = te * 4;
        int r = flat >> 4, c = flat & 15;
        *(float4*)&s_C[r][c] = *(const float4*)(xd + (size_t)(rowbase + r) * 48 + 32 + c);
    }

    const bf16_t* dptr = dlt + (size_t)rowbase * ED_ + e;
    const bf16_t* zptr = xz  + (size_t)rowbase * (2 * ED_) + ED_ + e;
    const float*  lptr = ylocal + (size_t)rowbase * ED_ + e;
    bf16_t*       optr = y + (size_t)rowbase * ED_ + e;

    if (seg == 0) {
        __syncthreads();
        #pragma unroll 8
        for (int l = 0; l < SLEN_; l++) {
            float yl = lptr[(size_t)l * ED_];
            float zv = b2f(zptr[(size_t)l * (2 * ED_)]);
            optr[(size_t)l * ED_] = __float2bfloat16(yl * siluf(zv));
        }
        return;
    }

    float A[16];
    {
        const float* ap = A_log + ((size_t)layer * ED_ + e) * NS_;
        #pragma unroll
        for (int n = 0; n < 16; n++) A[n] = -__expf(ap[n]);
    }

    // cross-segment stitch
    float hc[16];
    #pragma unroll
    for (int n = 0; n < 16; n++) hc[n] = 0.f;
    for (int s = 0; s < seg; s++) {
        #pragma unroll
        for (int n = 0; n < 16; n++) {
            size_t idx = ((((size_t)b * SEG_ + s) << 4) + n) * ED_ + e;
            hc[n] = fmaf(aprod[idx], hc[n], hend[idx]);
        }
    }

    bf16_t dvb[8], zvb[8]; float ylb[8];
    #pragma unroll
    for (int j = 0; j < 8; j++) {
        dvb[j] = dptr[(size_t)j * ED_];
        zvb[j] = zptr[(size_t)j * (2 * ED_)];
        ylb[j] = lptr[(size_t)j * ED_];
    }
    __syncthreads();

    for (int sub = 0; sub < 8; sub++) {
        bf16_t dnx[8], znx[8]; float ynx[8];
        if (sub < 7) {
            const bf16_t* d2 = dptr + (size_t)(sub + 1) * 8 * ED_;
            const bf16_t* z2 = zptr + (size_t)(sub + 1) * 8 * (2 * ED_);
            const float*  l2 = lptr + (size_t)(sub + 1) * 8 * ED_;
            #pragma unroll
            for (int j = 0; j < 8; j++) {
                dnx[j] = d2[(size_t)j * ED_];
                znx[j] = z2[(size_t)j * (2 * ED_)];
                ynx[j] = l2[(size_t)j * ED_];
            }
        }
        #pragma unroll
        for (int j = 0; j < 8; j++) {
            int l = sub * 8 + j;
            float dv = b2f(dvb[j]);
            float Cv[16];
            #pragma unroll
            for (int q = 0; q < 4; q++)
                *(float4*)&Cv[q * 4] = *(const float4*)&s_C[l][q * 4];
            float y0 = 0.f, y1 = 0.f, y2 = 0.f, y3 = 0.f;
            #pragma unroll
            for (int n = 0; n < 16; n++) {
                float a = __expf(dv * A[n]);
                hc[n] *= a;
                float t = Cv[n] * hc[n];
                if ((n & 3) == 0) y0 += t;
                else if ((n & 3) == 1) y1 += t;
                else if ((n & 3) == 2) y2 += t;
                else y3 += t;
            }
            float yl = ylb[j] + (y0 + y1) + (y2 + y3);
            float zv = b2f(zvb[j]);
            optr[(size_t)l * ED_] = __float2bfloat16(yl * siluf(zv));
        }
        #pragma unroll
        for (int j = 0; j < 8; j++) { dvb[j] = dnx[j]; zvb[j] = znx[j]; ylb[j] = ynx[j]; }
    }
}

// ---------------- final LN + head
__global__ void k_final(const float* __restrict__ x,
                        const float* __restrict__ fg, const float* __restrict__ fb,
                        const float* __restrict__ hw, const float* __restrict__ hb,
                        float* __restrict__ out) {
    __shared__ float sm[8];
    int row = blockIdx.x;
    int d = threadIdx.x;
    float v = x[row * DM_ + d];
    float2 s = block_sum256_2(v, v * v, sm);
    float mean = s.x * (1.0f / DM_);
    float var = s.y * (1.0f / DM_) - mean * mean;
    float rstd = rsqrtf(var + 1e-5f);
    float xf = (v - mean) * rstd * fg[d] + fb[d];
    float2 hsum = block_sum256_2(xf * hw[d * Q_ + 0], xf * hw[d * Q_ + 1], sm);
    if (d < Q_) {
        float sv = (d == 0) ? hsum.x : hsum.y;
        out[row * Q_ + d] = sv + hb[d];
    }
}

extern "C" void kernel_launch(void* const* d_in, const int* in_sizes, int n_in,
                              void* d_out, int out_size, void* d_ws, size_t ws_size,
                              hipStream_t stream) {
    const int*   tokens    = (const int*)d_in[0];
    const float* T         = (const float*)d_in[1];
    const float* tok_embed = (const float*)d_in[2];
    const float* pos_embed = (const float*)d_in[3];
    const float* tw1       = (const float*)d_in[4];
    const float* tb1       = (const float*)d_in[5];
    const float* tw2       = (const float*)d_in[6];
    const float* tb2       = (const float*)d_in[7];
    const float* ag        = (const float*)d_in[8];
    const float* ab        = (const float*)d_in[9];
    const float* apw       = (const float*)d_in[10];
    const float* apb       = (const float*)d_in[11];
    const float* in_w      = (const float*)d_in[12];
    const float* conv_w    = (const float*)d_in[13];
    const float* conv_b    = (const float*)d_in[14];
    const float* xp_w      = (const float*)d_in[15];
    const float* dt_w      = (const float*)d_in[16];
    const float* dt_b      = (const float*)d_in[17];
    const float* A_log     = (const float*)d_in[18];
    const float* Dp        = (const float*)d_in[19];
    const float* out_w     = (const float*)d_in[20];
    const float* fg        = (const float*)d_in[21];
    const float* fb        = (const float*)d_in[22];
    const float* hw        = (const float*)d_in[23];
    const float* hb        = (const float*)d_in[24];
    float* out = (float*)d_out;

    const int ROWS = B_ * L_;   // 8192

    char* p = (char*)d_ws;
    float*  x      = (float*)p;   p += (size_t)ROWS * DM_ * 4;
    bf16_t* xn     = (bf16_t*)p;  p += (size_t)ROWS * DM_ * 2;
    bf16_t* xz     = (bf16_t*)p;  p += (size_t)ROWS * 2 * ED_ * 2;
    bf16_t* xs     = (bf16_t*)p;  p += (size_t)ROWS * ED_ * 2;
    float*  xd     = (float*)p;   p += (size_t)ROWS * 48 * 4;
    bf16_t* dlt    = (bf16_t*)p;  p += (size_t)ROWS * ED_ * 2;
    bf16_t* y      = (bf16_t*)p;  p += (size_t)ROWS * ED_ * 2;
    float*  ylocal = (float*)p;   p += (size_t)ROWS * ED_ * 4;           // 16 MB
    float*  ss     = (float*)p;   p += (size_t)NL_ * B_ * 2 * DM_ * 4;
    float*  aprod  = (float*)p;   p += (size_t)B_ * SEG_ * NS_ * ED_ * 4;  // 4 MB
    float*  hend   = (float*)p;   p += (size_t)B_ * SEG_ * NS_ * ED_ * 4;  // 4 MB
    bf16_t* in_wT  = (bf16_t*)p;  p += (size_t)NL_ * 2 * ED_ * DM_ * 2;
    bf16_t* xp_wT  = (bf16_t*)p;  p += (size_t)NL_ * 48 * ED_ * 2;
    bf16_t* out_wT = (bf16_t*)p;  p += (size_t)NL_ * DM_ * ED_ * 2;

    k_transpose_all<<<dim3(32, 16, 12), 256, 0, stream>>>(
        in_w, xp_w, out_w, in_wT, xp_wT, out_wT);
    k_prep<<<dim3(B_, NL_), 2 * DM_, 0, stream>>>(T, tw1, tb1, tw2, tb2, apw, apb, ss);
    k_embed<<<ROWS, DM_, 0, stream>>>(tokens, tok_embed, pos_embed, x);

    for (int i = 0; i < NL_; i++) {
        k_lnmod<<<ROWS, DM_, 0, stream>>>(x, ag, ab, ss, xn, i);
        k_mfma_gemm<128, 128, true, false><<<dim3(2 * ED_ / 128, ROWS / 128), 256, 0, stream>>>(
            xn, in_wT + (size_t)i * 2 * ED_ * DM_, nullptr, xz, ROWS, 2 * ED_, DM_);
        k_conv<<<ROWS * (ED_ / 2) / 256, 256, 0, stream>>>(xz, conv_w, conv_b, xs, i);
        k_mfma_gemm<64, 64, false, false><<<dim3(1, ROWS / 64), 256, 0, stream>>>(
            xs, xp_wT + (size_t)i * 48 * ED_, xd, nullptr, ROWS, 48, ED_);
        k_dlt<<<ROWS * (ED_ / 2) / 256, 256, 0, stream>>>(xd, dt_w, dt_b, dlt, i);
        // chunked scan: thread-per-(b,e,seg), 16 states in registers
        k_scan1<<<B_ * 2 * SEG_, 256, 0, stream>>>(
            dlt, xs, xd, A_log, Dp, aprod, hend, ylocal, i);
        k_scan3<<<B_ * 2 * SEG_, 256, 0, stream>>>(
            dlt, xz, xd, A_log, aprod, hend, ylocal, y, i);
        k_mfma_gemm<128, 64, false, true><<<dim3(DM_ / 64, ROWS / 128), 256, 0, stream>>>(
            y, out_wT + (size_t)i * DM_ * ED_, x, nullptr, ROWS, DM_, ED_);
    }

    k_final<<<ROWS, DM_, 0, stream>>>(x, fg, fb, hw, hb, out);
}